// Round 14
// baseline (273.058 us; speedup 1.0000x reference)
//
#include <hip/hip_runtime.h>
#include <hip/hip_bf16.h>
#include <cstdint>
#include <cstddef>

#define T_ 512
#define DF 64
#define NPAIR 120
#define STEPW 16
#define NEGS (-(1 << 26))
#define RING 32   // LDS ring slots (64 KB); prefetch depth 16 rows
#define NSK 768   // skewed-W rows per pair (764 used, padded)

// softmin constants
#define C1_ 0.28853900817779268f   // log2(e)/5
#define C2D 3.4657359027997265     // 5*ln(2), double

__device__ __forceinline__ float wred_sum(float v) {
#pragma unroll
  for (int o = 32; o > 0; o >>= 1) v += __shfl_down(v, o);
  return v;  // lane 0 holds the total
}

__device__ __forceinline__ int dexp(double x) {
  // biased-exponent field - 1023; 0.0 -> -1023 (safe "very small" marker)
  return (int)((__double_as_longlong(x) >> 52) & 0x7ff) - 1023;
}

// async global->LDS DMA, 16 B per lane: LDS dest = base + lane*16 (HW),
// global src = per-lane address. Increments vmcnt.
__device__ __forceinline__ void dma16(const float* g, float* l) {
  __builtin_amdgcn_global_load_lds(
      (const __attribute__((address_space(1))) void*)g,
      (__attribute__((address_space(3))) void*)l, 16, 0, 0);
}

// ---------------------------------------------------------------------------
// Kernel 1: pairwise sq-dist GEMM; epilogue stores W = exp(-D/gamma) in
// STAGGER-SKEWED (4 rows/lane) + WITHIN-ROW-PERMUTED layout:
//   skew row n = i + 4*(j>>3); within row, lane g8's cols 8g8..8g8+3 at
//   float offset 4*g8, cols 8g8+4..+7 at 256+4*g8.
// The 4-row stagger gives the DTW boundary shuffle a full superstep of
// slack (r13 post-mortem: shuffle latency was ON the critical path).
// ---------------------------------------------------------------------------
__global__ __launch_bounds__(256) void gemm_kernel(
    const float* __restrict__ data, float* __restrict__ wbuf, int pair0) {
  __shared__ float Xs[64][65];
  __shared__ float Ys[64][65];
  __shared__ float nrmx[64];
  __shared__ float nrmy[64];

  const int tile = blockIdx.x;   // 0..63 = (bi<<3)|bj
  const int pc = blockIdx.y;     // pair within chunk
  const int p = pair0 + pc;
  const int w = p / 15;
  const int o = p - w * 15;
  const int aidx = w * STEPW;
  const int oidx = aidx + 1 + o;
  const int i0 = (tile >> 3) << 6;
  const int j0 = (tile & 7) << 6;
  const int tid = threadIdx.x;

  const float* Xg = data + (size_t)aidx * (T_ * DF);
  const float* Yg = data + (size_t)oidx * (T_ * DF);

#pragma unroll
  for (int l = 0; l < 4; ++l) {
    int idx = tid + l * 256;  // 0..1023
    int r = idx >> 4;
    int c = idx & 15;
    float4 xv = reinterpret_cast<const float4*>(Xg + (size_t)(i0 + r) * DF)[c];
    float4 yv = reinterpret_cast<const float4*>(Yg + (size_t)(j0 + r) * DF)[c];
    Xs[r][4 * c + 0] = xv.x; Xs[r][4 * c + 1] = xv.y;
    Xs[r][4 * c + 2] = xv.z; Xs[r][4 * c + 3] = xv.w;
    Ys[r][4 * c + 0] = yv.x; Ys[r][4 * c + 1] = yv.y;
    Ys[r][4 * c + 2] = yv.z; Ys[r][4 * c + 3] = yv.w;
  }
  __syncthreads();

  if (tid < 128) {
    int r = tid & 63;
    const float* row = (tid < 64) ? Xs[r] : Ys[r];
    float s = 0.f;
#pragma unroll
    for (int k = 0; k < 64; ++k) s = fmaf(row[k], row[k], s);
    if (tid < 64) nrmx[r] = s; else nrmy[r] = s;
  }
  __syncthreads();

  const int tx = tid & 15;
  const int ty = tid >> 4;
  float acc[4][4];
#pragma unroll
  for (int a = 0; a < 4; ++a)
#pragma unroll
    for (int b = 0; b < 4; ++b) acc[a][b] = 0.f;

#pragma unroll 4
  for (int k = 0; k < 64; ++k) {
    float xr[4], yr[4];
#pragma unroll
    for (int a = 0; a < 4; ++a) xr[a] = Xs[ty * 4 + a][k];
#pragma unroll
    for (int b = 0; b < 4; ++b) yr[b] = Ys[tx * 4 + b][k];
#pragma unroll
    for (int a = 0; a < 4; ++a)
#pragma unroll
      for (int b = 0; b < 4; ++b) acc[a][b] = fmaf(xr[a], yr[b], acc[a][b]);
  }

  // epilogue: my float4 (cols j0+4tx..+3) belongs to lane g8 = (j0>>3)+(tx>>1)
  const int g8 = (j0 >> 3) + (tx >> 1);
  const int off = ((tx & 1) << 8) + 4 * g8;
  float* Wp = wbuf + (size_t)pc * (NSK * T_) + off;
#pragma unroll
  for (int a = 0; a < 4; ++a) {
    int ii = ty * 4 + a;
    float nx = nrmx[ii];
    float4 v;
    v.x = __builtin_exp2f(-(nx + nrmy[tx * 4 + 0] - 2.f * acc[a][0]) * C1_);
    v.y = __builtin_exp2f(-(nx + nrmy[tx * 4 + 1] - 2.f * acc[a][1]) * C1_);
    v.z = __builtin_exp2f(-(nx + nrmy[tx * 4 + 2] - 2.f * acc[a][2]) * C1_);
    v.w = __builtin_exp2f(-(nx + nrmy[tx * 4 + 3] - 2.f * acc[a][3]) * C1_);
    *reinterpret_cast<float4*>(Wp + (size_t)(i0 + ii + 4 * g8) * T_) = v;
  }
}

// ---------------------------------------------------------------------------
// Kernel 2: softDTW, exp-domain fp64 + block exponent, 2 rows/superstep,
// 4-ROW STAGGER: lane l owns cols [8l,8l+8), superstep m does rows
// i=2m-4l, i+1 (i always even). Boundary values (lane l-1's rows i-1,i,i+1
// = its {B of m-3, A of m-2, B of m-2}) are complete at end of m-2, so the
// shuffle issued at start of m-1 is consumed at m -> one full superstep of
// slack, DS latency OFF the critical path (r13 post-mortem).
// W staging: 32-slot LDS ring, coalesced DMAs, wait vmcnt(24), never drain.
// ---------------------------------------------------------------------------
__global__ __launch_bounds__(64) void dtw_kernel(
    const float* __restrict__ Wm, const int* __restrict__ lens,
    float* __restrict__ dist, int pair0) {
  __shared__ float slot[RING * T_];  // 32 slots x 2048 B = 64 KB

  const int pc = blockIdx.x;
  const int p = pair0 + pc;
  const int w = p / 15;
  const int o = p - w * 15;
  const int lx = lens[w * STEPW];
  const int ly = lens[w * STEPW + 1 + o];
  const int l = threadIdx.x;
  const int imax = lx - 1;
  const int jt = ly - 1;
  const int lt = jt >> 3, ct = jt & 7;
  const int M = 2 * lt + (imax >> 1);  // last superstep needed by lane lt
  const float invl = 1.f / (float)(lx + ly);

  const float* wp = Wm + (size_t)pc * (NSK * T_);

  // one skewed row R -> slot R%32 (2 x 1KB coalesced DMAs)
#define ISSUE(R)                                                       \
  {                                                                    \
    int r_ = (R);                                                      \
    r_ = (r_ > 763) ? 763 : r_;                                        \
    const float* gb_ = wp + (size_t)r_ * T_ + (l << 2);                \
    float* lb_ = &slot[((R) & (RING - 1)) * T_];                       \
    dma16(gb_, lb_);                                                   \
    dma16(gb_ + 256, lb_ + 256);                                       \
  }

  // prologue: rows 0..15 in flight (32 DMAs)
  ISSUE(0);  ISSUE(1);  ISSUE(2);  ISSUE(3);
  ISSUE(4);  ISSUE(5);  ISSUE(6);  ISSUE(7);
  ISSUE(8);  ISSUE(9);  ISSUE(10); ISSUE(11);
  ISSUE(12); ISSUE(13); ISSUE(14); ISSUE(15);

  // committed-row E (fp64 mantissas, shared block exponent S)
  double e0 = 0., e1 = 0., e2 = 0., e3 = 0.;
  double e4 = 0., e5 = 0., e6 = 0., e7 = 0.;
  double e7A = 0.;            // row-A e7 of current committed pair
  double e7_old = 0.;         // my B-row e7 of PREVIOUS superstep
  int S = NEGS, S_old = NEGS;

  // boundary regs consumed THIS superstep (shuffled at m-1, data of m-2/m-3)
  double bndA = 0., bndB = 0., bndP = 0.;
  int bS = NEGS, bSP = NEGS;

  // wait rows 0,1; read them as current W regs
  asm volatile("s_waitcnt vmcnt(28)" ::: "memory");
  __builtin_amdgcn_sched_barrier(0);
  float4 cA0 = *reinterpret_cast<const float4*>(&slot[0 * T_ + 4 * l]);
  float4 cA1 = *reinterpret_cast<const float4*>(&slot[0 * T_ + 256 + 4 * l]);
  float4 cB0 = *reinterpret_cast<const float4*>(&slot[1 * T_ + 4 * l]);
  float4 cB1 = *reinterpret_cast<const float4*>(&slot[1 * T_ + 256 + 4 * l]);

  for (int m = 0; m <= M; ++m) {
    // shuffle lane l-1's end-of-(m-1) state; consumed at superstep m+1
    double nInP = __shfl_up(e7_old, 1);
    int nInSP = __shfl_up(S_old, 1);
    double nInA = __shfl_up(e7A, 1);
    double nInB = __shfl_up(e7, 1);
    int nInS = __shfl_up(S, 1);
    e7_old = e7; S_old = S;  // B of m-1 becomes "old" before overwrite

    const int i = 2 * m - 4 * l;

    // boundary operands for THIS superstep (from bnd regs, 1 superstep old)
    double lA = bndA, dA = bndP, lB = bndB, dB2 = bndA;
    int slA = bS, sdA = bSP, slB = bS, sdB = bS;
    if (l == 0) {
      lA = 0.; slA = NEGS;
      dA = (i == 0) ? 1. : 0.; sdA = (i == 0) ? 0 : NEGS;
      lB = 0.; slB = NEGS;
      dB2 = 0.; sdB = NEGS;
    }

    // rows 2m+2, 2m+3 guaranteed done; read next superstep's rows, refill
    asm volatile("s_waitcnt vmcnt(24)" ::: "memory");
    __builtin_amdgcn_sched_barrier(0);
    const int sN0 = ((2 * m + 2) & (RING - 1)) * T_;
    const int sN1 = ((2 * m + 3) & (RING - 1)) * T_;
    float4 nA0 = *reinterpret_cast<const float4*>(&slot[sN0 + 4 * l]);
    float4 nA1 = *reinterpret_cast<const float4*>(&slot[sN0 + 256 + 4 * l]);
    float4 nB0 = *reinterpret_cast<const float4*>(&slot[sN1 + 4 * l]);
    float4 nB1 = *reinterpret_cast<const float4*>(&slot[sN1 + 256 + 4 * l]);
    ISSUE(2 * m + 16);
    ISSUE(2 * m + 17);

    if ((unsigned)i <= (unsigned)imax) {
      // ---- row A (i), full sum-based rescale (r6 lesson: sum bounds max)
      double sum = ((e0 + e1) + (e2 + e3)) + ((e4 + e5) + (e6 + e7));
      int NA = max(S + dexp(sum), max(slA + dexp(lA), sdA + dexp(dA)));
      const int dS = S - NA;
      if (dS != 0) {
        e0 = ldexp(e0, dS); e1 = ldexp(e1, dS);
        e2 = ldexp(e2, dS); e3 = ldexp(e3, dS);
        e4 = ldexp(e4, dS); e5 = ldexp(e5, dS);
        e6 = ldexp(e6, dS); e7 = ldexp(e7, dS);
      }
      double L = ldexp(lA, slA - NA);
      double G = ldexp(dA, sdA - NA);
      const double WA0 = (double)cA0.x, WA1 = (double)cA0.y;
      const double WA2 = (double)cA0.z, WA3 = (double)cA0.w;
      const double WA4 = (double)cA1.x, WA5 = (double)cA1.y;
      const double WA6 = (double)cA1.z, WA7 = (double)cA1.w;
      double qa0 = WA0 * ((L + G) + e0);
      double qa1 = WA1 * (e1 + e0);
      double qa2 = WA2 * (e2 + e1);
      double qa3 = WA3 * (e3 + e2);
      double qa4 = WA4 * (e4 + e3);
      double qa5 = WA5 * (e5 + e4);
      double qa6 = WA6 * (e6 + e5);
      double qa7 = WA7 * (e7 + e6);
      double a0 = qa0;
      double a1 = fma(WA1, a0, qa1);
      double a2 = fma(WA2, a1, qa2);
      double a3 = fma(WA3, a2, qa3);
      double a4 = fma(WA4, a3, qa4);
      double a5 = fma(WA5, a4, qa5);
      double a6 = fma(WA6, a5, qa6);
      double a7 = fma(WA7, a6, qa7);

      if (i + 1 <= imax) {
        // ---- row B (i+1), light scale update (boundary-max guard kept)
        int NB = max(NA, max(slB + dexp(lB), sdB + dexp(dB2)));
        const int dB = NA - NB;
        if (dB != 0) {
          a0 = ldexp(a0, dB); a1 = ldexp(a1, dB);
          a2 = ldexp(a2, dB); a3 = ldexp(a3, dB);
          a4 = ldexp(a4, dB); a5 = ldexp(a5, dB);
          a6 = ldexp(a6, dB); a7 = ldexp(a7, dB);
        }
        double LB = ldexp(lB, slB - NB);
        double GB = ldexp(dB2, sdB - NB);
        const double WB0 = (double)cB0.x, WB1 = (double)cB0.y;
        const double WB2 = (double)cB0.z, WB3 = (double)cB0.w;
        const double WB4 = (double)cB1.x, WB5 = (double)cB1.y;
        const double WB6 = (double)cB1.z, WB7 = (double)cB1.w;
        double qb0 = WB0 * ((LB + GB) + a0);
        double qb1 = WB1 * (a1 + a0);
        double qb2 = WB2 * (a2 + a1);
        double qb3 = WB3 * (a3 + a2);
        double qb4 = WB4 * (a4 + a3);
        double qb5 = WB5 * (a5 + a4);
        double qb6 = WB6 * (a6 + a5);
        double qb7 = WB7 * (a7 + a6);
        e0 = qb0;
        e1 = fma(WB1, e0, qb1);
        e2 = fma(WB2, e1, qb2);
        e3 = fma(WB3, e2, qb3);
        e4 = fma(WB4, e3, qb4);
        e5 = fma(WB5, e4, qb5);
        e6 = fma(WB6, e5, qb6);
        e7 = fma(WB7, e6, qb7);
        e7A = a7;  // already aligned to NB
        S = NB;
      } else {
        // row B out of range: commit row A as the final row
        e0 = a0; e1 = a1; e2 = a2; e3 = a3;
        e4 = a4; e5 = a5; e6 = a6; e7 = a7;
        e7A = a7;
        S = NA;
      }
    }
    // advance boundary pipeline + W registers
    bndP = nInP; bndA = nInA; bndB = nInB; bS = nInS; bSP = nInSP;
    cA0 = nA0; cA1 = nA1; cB0 = nB0; cB1 = nB1;
  }

  // drain: outstanding DMAs must not land in a successor block's LDS
  asm volatile("s_waitcnt vmcnt(0)" ::: "memory");

  if (l == lt) {
    double out_v = (ct == 0) ? e0 : (ct == 1) ? e1 : (ct == 2) ? e2
                 : (ct == 3) ? e3 : (ct == 4) ? e4 : (ct == 5) ? e5
                 : (ct == 6) ? e6 : e7;
    double vv = (out_v > 0.) ? out_v : 1e-300;  // belt-and-braces
    double r = -C2D * (log2(vv) + (double)S);
    dist[p] = (float)(r * (double)invl);
  }
}

// ---------------------------------------------------------------------------
// Kernel 3: MMD pairwise per-feature L2 (upper triangle, mirrored)
// ---------------------------------------------------------------------------
__global__ __launch_bounds__(64) void mmd_l2_kernel(
    const float* __restrict__ data, float* __restrict__ l2buf,
    float* __restrict__ bwpart) {
  int b = blockIdx.x;  // 0..252 upper-tri (incl diag) index
  int u = 0, rem = b;
  while (rem >= 22 - u) { rem -= 22 - u; ++u; }
  int v = u + rem;
  int f = threadIdx.x;
  float s = 0.f;
  if (u != v) {
    int iu = u < 11 ? u : u + 5;
    int iv = v < 11 ? v : v + 5;
    const float* A = data + (size_t)iu * (T_ * DF) + f;
    const float* B = data + (size_t)iv * (T_ * DF) + f;
#pragma unroll 8
    for (int t = 0; t < T_; ++t) {
      float dd = A[(size_t)t * DF] - B[(size_t)t * DF];
      s = fmaf(dd, dd, s);
    }
  }
  l2buf[(size_t)(u * 22 + v) * 64 + f] = s;
  l2buf[(size_t)(v * 22 + u) * 64 + f] = s;
  float tot = wred_sum(s);
  if (f == 0) bwpart[b] = 2.f * tot;  // diag contributes exactly 0
}

// ---------------------------------------------------------------------------
// Kernel 4: MMD kernel sums per (a,c) of the 11x11 grid
// ---------------------------------------------------------------------------
__global__ __launch_bounds__(64) void mmd_k_kernel(
    const float* __restrict__ l2buf, const float* __restrict__ bwpart,
    float* __restrict__ mmdpart) {
  int b = blockIdx.x;  // 0..120
  int a = b / 11, c = b - a * 11;
  int f = threadIdx.x;
  float bs = 0.f;
  for (int k2 = f; k2 < 253; k2 += 64) bs += bwpart[k2];
  bs = wred_sum(bs);
  float bw = __shfl(bs, 0) * (1.f / (462.f * 4.f));  // /(n^2-n)/KMUL^(KNUM//2)
  float xx = l2buf[(size_t)(a * 22 + c) * 64 + f];
  float yy = l2buf[(size_t)((11 + a) * 22 + (11 + c)) * 64 + f];
  float xy = l2buf[(size_t)(a * 22 + (11 + c)) * 64 + f];
  float yx = l2buf[(size_t)((11 + a) * 22 + c) * 64 + f];
  float term = 0.f;
  float ib = 1.f / bw;
#pragma unroll
  for (int i = 0; i < 5; ++i) {
    term += expf(-xx * ib) + expf(-yy * ib) - expf(-xy * ib) - expf(-yx * ib);
    ib *= 0.5f;
  }
  float tt = wred_sum(term);
  if (f == 0) mmdpart[b] = tt;
}

// ---------------------------------------------------------------------------
// Kernel 5: finalize — triplet loss + variance + MMD mean -> out[0]
// ---------------------------------------------------------------------------
__global__ __launch_bounds__(64) void finalize_kernel(
    const float* __restrict__ dist, const float* __restrict__ mmdpart,
    float* __restrict__ out) {
  int lane = threadIdx.x;
  float lv_po = 0.f;
  float dg[5];
#pragma unroll
  for (int g = 0; g < 5; ++g) dg[g] = 0.f;
  if (lane < 8) {
    const float* dr = dist + lane * 15;
    float dn[10];
#pragma unroll
    for (int g = 0; g < 5; ++g) dg[g] = dr[g];
#pragma unroll
    for (int k = 0; k < 10; ++k) dn[k] = dr[5 + k];
    float s1 = 0.f, s2 = 0.f;
    int nz = 0;
#pragma unroll
    for (int g = 0; g < 5; ++g) {
#pragma unroll
      for (int k = 0; k < 5; ++k) {
        float v2 = dg[g] + 1.0f - dn[k];
        if (v2 > 0.f) { s1 += v2; ++nz; }
      }
#pragma unroll
      for (int k = 5; k < 10; ++k) {
        float v2 = dg[g] + 1.0f - dn[k];
        if (v2 > 0.f) { s2 += v2; ++nz; }
      }
    }
    float only_pos = (dg[0] + dg[1] + dg[2] + dg[3] + dg[4]) * 0.002f;
    float lv = (s1 * 0.7f + s2 * 0.3f) / (float)(nz + 1);
    lv_po = lv + only_pos;
  }
  float tl = wred_sum(lv_po);
  tl = __shfl(tl, 0);

  // two-pass ddof=1 variance over the 40 dg values
  float psum = dg[0] + dg[1] + dg[2] + dg[3] + dg[4];
  float tsum = wred_sum(psum);
  float mean = __shfl(tsum, 0) * (1.f / 40.f);
  float pdev = 0.f;
  if (lane < 8) {
#pragma unroll
    for (int g = 0; g < 5; ++g) {
      float dd = dg[g] - mean;
      pdev = fmaf(dd, dd, pdev);
    }
  }
  float tdev = wred_sum(pdev);
  tdev = __shfl(tdev, 0);

  float msum = 0.f;
  for (int k2 = lane; k2 < 121; k2 += 64) msum += mmdpart[k2];
  float mt = wred_sum(msum);

  if (lane == 0) {
    float total_loss = tl * (1.f / 8.f);
    float var_g = (tdev / 39.f) * 0.1f;
    float mmd = mt * (1.f / 7744.f);
    out[0] = total_loss + mmd + var_g;
  }
}

__global__ __launch_bounds__(64) void zero_out_kernel(float* __restrict__ out,
                                                      int n) {
  int i = blockIdx.x * 64 + threadIdx.x;
  if (i < n) out[i] = 0.f;
}

// ---------------------------------------------------------------------------
extern "C" void kernel_launch(void* const* d_in, const int* in_sizes, int n_in,
                              void* d_out, int out_size, void* d_ws,
                              size_t ws_size, hipStream_t stream) {
  const float* data = (const float*)d_in[0];
  const int* lens = (const int*)d_in[1];
  float* out = (float*)d_out;
  char* ws = (char*)d_ws;

  const size_t HDR = 131072;  // dist/bwpart/mmdpart/l2buf region
  const size_t per_pair = (size_t)NSK * T_ * sizeof(float);  // 1.57 MB

  // Strict workspace guard: never touch bytes beyond ws_size.
  if (ws_size < HDR + per_pair) {
    zero_out_kernel<<<dim3((out_size + 63) / 64), 64, 0, stream>>>(out,
                                                                   out_size);
    return;
  }

  float* dist = (float*)(ws + 0);        // 120 floats
  float* bwpart = (float*)(ws + 1024);   // 253 floats
  float* mmdpart = (float*)(ws + 3072);  // 121 floats
  float* l2buf = (float*)(ws + 4096);    // 22*22*64 floats = 123904 B
  float* wbuf = (float*)(ws + HDR);

  size_t avail = ws_size - HDR;
  int PC = (int)(avail / per_pair);
  if (PC > NPAIR) PC = NPAIR;

  for (int p0 = 0; p0 < NPAIR; p0 += PC) {
    int pc = (NPAIR - p0) < PC ? (NPAIR - p0) : PC;
    gemm_kernel<<<dim3(64, pc), 256, 0, stream>>>(data, wbuf, p0);
    dtw_kernel<<<dim3(pc), 64, 0, stream>>>(wbuf, lens, dist, p0);
  }
  mmd_l2_kernel<<<dim3(253), 64, 0, stream>>>(data, l2buf, bwpart);
  mmd_k_kernel<<<dim3(121), 64, 0, stream>>>(l2buf, bwpart, mmdpart);
  finalize_kernel<<<dim3(1), 64, 0, stream>>>(dist, mmdpart, out);
}

// Round 15
// 229.886 us; speedup vs baseline: 1.1878x; 1.1878x over previous
//
#include <hip/hip_runtime.h>
#include <hip/hip_bf16.h>
#include <cstdint>
#include <cstddef>

#define T_ 512
#define DF 64
#define NPAIR 120
#define STEPW 16
#define NEGS (-(1 << 26))
#define NSK 640   // skewed-W rows per pair (638 used, padded)

// softmin constants
#define C1_ 0.28853900817779268f   // log2(e)/5
#define C2D 3.4657359027997265     // 5*ln(2), double

__device__ __forceinline__ float wred_sum(float v) {
#pragma unroll
  for (int o = 32; o > 0; o >>= 1) v += __shfl_down(v, o);
  return v;  // lane 0 holds the total
}

__device__ __forceinline__ int dexp(double x) {
  // biased-exponent field - 1023; 0.0 -> -1023 (safe "very small" marker)
  return (int)((__double_as_longlong(x) >> 52) & 0x7ff) - 1023;
}

// unsinkable 16B global load to a named VGPR quad (HK pattern). Data is NOT
// valid until a manual s_waitcnt vmcnt(N); rule-18: sched_barrier after wait.
#define GLOAD(DST, PTR)                                                    \
  asm volatile("global_load_dwordx4 %0, %1, off"                           \
               : "=&v"(DST) : "v"(PTR) : "memory")

// ---------------------------------------------------------------------------
// Kernel 1: pairwise sq-dist GEMM; epilogue stores W = exp(-D/gamma) in
// STAGGER-SKEWED (2 rows/lane) + WITHIN-ROW-PERMUTED layout:
//   skew row n = i + 2*(j>>3); within row, lane g8's cols 8g8..8g8+3 at
//   float offset 4*g8, cols 8g8+4..+7 at 256+4*g8.  (r13-verified)
// ---------------------------------------------------------------------------
__global__ __launch_bounds__(256) void gemm_kernel(
    const float* __restrict__ data, float* __restrict__ wbuf, int pair0) {
  __shared__ float Xs[64][65];
  __shared__ float Ys[64][65];
  __shared__ float nrmx[64];
  __shared__ float nrmy[64];

  const int tile = blockIdx.x;   // 0..63 = (bi<<3)|bj
  const int pc = blockIdx.y;     // pair within chunk
  const int p = pair0 + pc;
  const int w = p / 15;
  const int o = p - w * 15;
  const int aidx = w * STEPW;
  const int oidx = aidx + 1 + o;
  const int i0 = (tile >> 3) << 6;
  const int j0 = (tile & 7) << 6;
  const int tid = threadIdx.x;

  const float* Xg = data + (size_t)aidx * (T_ * DF);
  const float* Yg = data + (size_t)oidx * (T_ * DF);

#pragma unroll
  for (int l = 0; l < 4; ++l) {
    int idx = tid + l * 256;  // 0..1023
    int r = idx >> 4;
    int c = idx & 15;
    float4 xv = reinterpret_cast<const float4*>(Xg + (size_t)(i0 + r) * DF)[c];
    float4 yv = reinterpret_cast<const float4*>(Yg + (size_t)(j0 + r) * DF)[c];
    Xs[r][4 * c + 0] = xv.x; Xs[r][4 * c + 1] = xv.y;
    Xs[r][4 * c + 2] = xv.z; Xs[r][4 * c + 3] = xv.w;
    Ys[r][4 * c + 0] = yv.x; Ys[r][4 * c + 1] = yv.y;
    Ys[r][4 * c + 2] = yv.z; Ys[r][4 * c + 3] = yv.w;
  }
  __syncthreads();

  if (tid < 128) {
    int r = tid & 63;
    const float* row = (tid < 64) ? Xs[r] : Ys[r];
    float s = 0.f;
#pragma unroll
    for (int k = 0; k < 64; ++k) s = fmaf(row[k], row[k], s);
    if (tid < 64) nrmx[r] = s; else nrmy[r] = s;
  }
  __syncthreads();

  const int tx = tid & 15;
  const int ty = tid >> 4;
  float acc[4][4];
#pragma unroll
  for (int a = 0; a < 4; ++a)
#pragma unroll
    for (int b = 0; b < 4; ++b) acc[a][b] = 0.f;

#pragma unroll 4
  for (int k = 0; k < 64; ++k) {
    float xr[4], yr[4];
#pragma unroll
    for (int a = 0; a < 4; ++a) xr[a] = Xs[ty * 4 + a][k];
#pragma unroll
    for (int b = 0; b < 4; ++b) yr[b] = Ys[tx * 4 + b][k];
#pragma unroll
    for (int a = 0; a < 4; ++a)
#pragma unroll
      for (int b = 0; b < 4; ++b) acc[a][b] = fmaf(xr[a], yr[b], acc[a][b]);
  }

  // epilogue: my float4 (cols j0+4tx..+3) belongs to lane g8 = (j0>>3)+(tx>>1)
  const int g8 = (j0 >> 3) + (tx >> 1);
  const int off = ((tx & 1) << 8) + 4 * g8;
  float* Wp = wbuf + (size_t)pc * (NSK * T_) + off;
#pragma unroll
  for (int a = 0; a < 4; ++a) {
    int ii = ty * 4 + a;
    float nx = nrmx[ii];
    float4 v;
    v.x = __builtin_exp2f(-(nx + nrmy[tx * 4 + 0] - 2.f * acc[a][0]) * C1_);
    v.y = __builtin_exp2f(-(nx + nrmy[tx * 4 + 1] - 2.f * acc[a][1]) * C1_);
    v.z = __builtin_exp2f(-(nx + nrmy[tx * 4 + 2] - 2.f * acc[a][2]) * C1_);
    v.w = __builtin_exp2f(-(nx + nrmy[tx * 4 + 3] - 2.f * acc[a][3]) * C1_);
    *reinterpret_cast<float4*>(Wp + (size_t)(i0 + ii + 2 * g8) * T_) = v;
  }
}

// ---------------------------------------------------------------------------
// Kernel 2: softDTW, exp-domain fp64 + block exponent, 2 rows/superstep,
// r13 geometry, but W staged DIRECTLY IN REGISTERS: 12 named float4-pair
// row slots, modulo-scheduled (unroll 6), loads via asm-volatile
// global_load_dwordx4 (unsinkable; r5/r7 compiler-sinking impossible),
// hand-counted s_waitcnt vmcnt(12). r9..r14 post-mortems: per-superstep
// time was pinned at ~250cy PER global_load_lds regardless of address
// pattern/VALU/shuffles -> shallow per-wave LDS-DMA queue was the clock.
// Plain VMEM loads have deep per-wave MLP; no LDS involved at all.
// ---------------------------------------------------------------------------
__global__ __launch_bounds__(64) void dtw_kernel(
    const float* __restrict__ Wm, const int* __restrict__ lens,
    float* __restrict__ dist, int pair0) {
  const int pc = blockIdx.x;
  const int p = pair0 + pc;
  const int w = p / 15;
  const int o = p - w * 15;
  const int lx = lens[w * STEPW];
  const int ly = lens[w * STEPW + 1 + o];
  const int l = threadIdx.x;
  const int imax = lx - 1;
  const int jt = ly - 1;
  const int lt = jt >> 3, ct = jt & 7;
  const int M = lt + (imax >> 1);  // last superstep needed by lane lt
  const float invl = 1.f / (float)(lx + ly);

  const float* wp = Wm + (size_t)pc * (NSK * T_) + 4 * l;

  // 12 row slots, 2 float4 each (96 VGPRs): row R -> slot R%12
  float4 K0a, K0b, K1a, K1b, K2a, K2b, K3a, K3b;
  float4 K4a, K4b, K5a, K5b, K6a, K6b, K7a, K7b;
  float4 K8a, K8b, K9a, K9b, K10a, K10b, K11a, K11b;

#define LDROW(A, B, R)                                     \
  {                                                        \
    int r_ = (R); r_ = r_ > 637 ? 637 : r_;                \
    const float* p_ = wp + (size_t)r_ * T_;                \
    GLOAD(A, p_); GLOAD(B, p_ + 256);                      \
  }

  // prologue: rows 0..5 in flight (12 loads)
  LDROW(K0a, K0b, 0); LDROW(K1a, K1b, 1);
  LDROW(K2a, K2b, 2); LDROW(K3a, K3b, 3);
  LDROW(K4a, K4b, 4); LDROW(K5a, K5b, 5);

  // committed-row E (fp64 mantissas, shared block exponent S)
  double e0 = 0., e1 = 0., e2 = 0., e3 = 0.;
  double e4 = 0., e5 = 0., e6 = 0., e7 = 0.;
  double e7A = 0.;            // row-A e7 of current committed pair
  int S = NEGS;
  double pvB = 0.;  int psB = NEGS;  // 1-superstep-delayed neighbor row-B

  // superstep m: consume rows 2m,2m+1 (slots (2m)%12,(2m+1)%12); issue rows
  // 2m+6,2m+7 (consumed at m+3: ~3 supersteps ~1100cy lead >= L3 latency).
  // vmcnt: top of superstep 12 outstanding (rows 2m..2m+5); issue 2 rows ->
  // 16; wait vmcnt(12) retires rows 2m,2m+1 (in-order) -> 12 = rows
  // 2m+2..2m+7. Invariant holds at m+1. Final drain before dist store.
#define SUP(MM, SA0, SA1, SB0, SB1, RA0, RA1, RB0, RB1)                    \
  {                                                                        \
    const int m_ = (MM);                                                   \
    double nvA = __shfl_up(e7A, 1);                                        \
    double nvB = __shfl_up(e7, 1);                                         \
    int ns = __shfl_up(S, 1);                                              \
    LDROW(RA0, RA1, 2 * m_ + 6);                                           \
    LDROW(RB0, RB1, 2 * m_ + 7);                                           \
    asm volatile("s_waitcnt vmcnt(12)" ::: "memory");                      \
    __builtin_amdgcn_sched_barrier(0);                                     \
    const int i = 2 * (m_ - l);                                            \
    double lA = nvA, dA = pvB, lB = nvB, dB2 = nvA;                        \
    int slA = ns, sdA = psB, slB = ns, sdB = ns;                           \
    if (l == 0) {                                                          \
      lA = 0.; slA = NEGS;                                                 \
      dA = (i == 0) ? 1. : 0.; sdA = (i == 0) ? 0 : NEGS;                  \
      lB = 0.; slB = NEGS;                                                 \
      dB2 = 0.; sdB = NEGS;                                                \
    }                                                                      \
    if ((unsigned)i <= (unsigned)imax) {                                   \
      double sum = ((e0 + e1) + (e2 + e3)) + ((e4 + e5) + (e6 + e7));      \
      int NA = max(S + dexp(sum), max(slA + dexp(lA), sdA + dexp(dA)));    \
      const int dS = S - NA;                                               \
      if (dS != 0) {                                                       \
        e0 = ldexp(e0, dS); e1 = ldexp(e1, dS);                            \
        e2 = ldexp(e2, dS); e3 = ldexp(e3, dS);                            \
        e4 = ldexp(e4, dS); e5 = ldexp(e5, dS);                            \
        e6 = ldexp(e6, dS); e7 = ldexp(e7, dS);                            \
      }                                                                    \
      double L = ldexp(lA, slA - NA);                                      \
      double G = ldexp(dA, sdA - NA);                                      \
      const double WA0 = (double)SA0.x, WA1 = (double)SA0.y;               \
      const double WA2 = (double)SA0.z, WA3 = (double)SA0.w;               \
      const double WA4 = (double)SA1.x, WA5 = (double)SA1.y;               \
      const double WA6 = (double)SA1.z, WA7 = (double)SA1.w;               \
      double qa0 = WA0 * ((L + G) + e0);                                   \
      double qa1 = WA1 * (e1 + e0);                                        \
      double qa2 = WA2 * (e2 + e1);                                        \
      double qa3 = WA3 * (e3 + e2);                                        \
      double qa4 = WA4 * (e4 + e3);                                        \
      double qa5 = WA5 * (e5 + e4);                                        \
      double qa6 = WA6 * (e6 + e5);                                        \
      double qa7 = WA7 * (e7 + e6);                                        \
      double a0 = qa0;                                                     \
      double a1 = fma(WA1, a0, qa1);                                       \
      double a2 = fma(WA2, a1, qa2);                                       \
      double a3 = fma(WA3, a2, qa3);                                       \
      double a4 = fma(WA4, a3, qa4);                                       \
      double a5 = fma(WA5, a4, qa5);                                       \
      double a6 = fma(WA6, a5, qa6);                                       \
      double a7 = fma(WA7, a6, qa7);                                       \
      if (i + 1 <= imax) {                                                 \
        int NB = max(NA, max(slB + dexp(lB), sdB + dexp(dB2)));            \
        const int dB = NA - NB;                                            \
        if (dB != 0) {                                                     \
          a0 = ldexp(a0, dB); a1 = ldexp(a1, dB);                          \
          a2 = ldexp(a2, dB); a3 = ldexp(a3, dB);                          \
          a4 = ldexp(a4, dB); a5 = ldexp(a5, dB);                          \
          a6 = ldexp(a6, dB); a7 = ldexp(a7, dB);                          \
        }                                                                  \
        double LB = ldexp(lB, slB - NB);                                   \
        double GB = ldexp(dB2, sdB - NB);                                  \
        const double WB0 = (double)SB0.x, WB1 = (double)SB0.y;             \
        const double WB2 = (double)SB0.z, WB3 = (double)SB0.w;             \
        const double WB4 = (double)SB1.x, WB5 = (double)SB1.y;             \
        const double WB6 = (double)SB1.z, WB7 = (double)SB1.w;             \
        double qb0 = WB0 * ((LB + GB) + a0);                               \
        double qb1 = WB1 * (a1 + a0);                                      \
        double qb2 = WB2 * (a2 + a1);                                      \
        double qb3 = WB3 * (a3 + a2);                                      \
        double qb4 = WB4 * (a4 + a3);                                      \
        double qb5 = WB5 * (a5 + a4);                                      \
        double qb6 = WB6 * (a6 + a5);                                      \
        double qb7 = WB7 * (a7 + a6);                                      \
        e0 = qb0;                                                          \
        e1 = fma(WB1, e0, qb1);                                            \
        e2 = fma(WB2, e1, qb2);                                            \
        e3 = fma(WB3, e2, qb3);                                            \
        e4 = fma(WB4, e3, qb4);                                            \
        e5 = fma(WB5, e4, qb5);                                            \
        e6 = fma(WB6, e5, qb6);                                            \
        e7 = fma(WB7, e6, qb7);                                            \
        e7A = a7;  /* already aligned to NB */                             \
        S = NB;                                                            \
      } else {                                                             \
        e0 = a0; e1 = a1; e2 = a2; e3 = a3;                                \
        e4 = a4; e5 = a5; e6 = a6; e7 = a7;                                \
        e7A = a7;                                                          \
        S = NA;                                                            \
      }                                                                    \
    }                                                                      \
    pvB = nvB; psB = ns;                                                   \
  }

  const int nsup = (M + 6) / 6 * 6;  // covers m = 0..M
  for (int mb = 0; mb < nsup; mb += 6) {
    SUP(mb + 0, K0a, K0b, K1a, K1b, K6a, K6b, K7a, K7b);
    SUP(mb + 1, K2a, K2b, K3a, K3b, K8a, K8b, K9a, K9b);
    SUP(mb + 2, K4a, K4b, K5a, K5b, K10a, K10b, K11a, K11b);
    SUP(mb + 3, K6a, K6b, K7a, K7b, K0a, K0b, K1a, K1b);
    SUP(mb + 4, K8a, K8b, K9a, K9b, K2a, K2b, K3a, K3b);
    SUP(mb + 5, K10a, K10b, K11a, K11b, K4a, K4b, K5a, K5b);
  }

  // drain all outstanding loads before the store (vmcnt counts stores too)
  asm volatile("s_waitcnt vmcnt(0)" ::: "memory");

  if (l == lt) {
    double out_v = (ct == 0) ? e0 : (ct == 1) ? e1 : (ct == 2) ? e2
                 : (ct == 3) ? e3 : (ct == 4) ? e4 : (ct == 5) ? e5
                 : (ct == 6) ? e6 : e7;
    double vv = (out_v > 0.) ? out_v : 1e-300;  // belt-and-braces
    double r = -C2D * (log2(vv) + (double)S);
    dist[p] = (float)(r * (double)invl);
  }
}

// ---------------------------------------------------------------------------
// Kernel 3: MMD pairwise per-feature L2 (upper triangle, mirrored)
// ---------------------------------------------------------------------------
__global__ __launch_bounds__(64) void mmd_l2_kernel(
    const float* __restrict__ data, float* __restrict__ l2buf,
    float* __restrict__ bwpart) {
  int b = blockIdx.x;  // 0..252 upper-tri (incl diag) index
  int u = 0, rem = b;
  while (rem >= 22 - u) { rem -= 22 - u; ++u; }
  int v = u + rem;
  int f = threadIdx.x;
  float s = 0.f;
  if (u != v) {
    int iu = u < 11 ? u : u + 5;
    int iv = v < 11 ? v : v + 5;
    const float* A = data + (size_t)iu * (T_ * DF) + f;
    const float* B = data + (size_t)iv * (T_ * DF) + f;
#pragma unroll 8
    for (int t = 0; t < T_; ++t) {
      float dd = A[(size_t)t * DF] - B[(size_t)t * DF];
      s = fmaf(dd, dd, s);
    }
  }
  l2buf[(size_t)(u * 22 + v) * 64 + f] = s;
  l2buf[(size_t)(v * 22 + u) * 64 + f] = s;
  float tot = wred_sum(s);
  if (f == 0) bwpart[b] = 2.f * tot;  // diag contributes exactly 0
}

// ---------------------------------------------------------------------------
// Kernel 4: MMD kernel sums per (a,c) of the 11x11 grid
// ---------------------------------------------------------------------------
__global__ __launch_bounds__(64) void mmd_k_kernel(
    const float* __restrict__ l2buf, const float* __restrict__ bwpart,
    float* __restrict__ mmdpart) {
  int b = blockIdx.x;  // 0..120
  int a = b / 11, c = b - a * 11;
  int f = threadIdx.x;
  float bs = 0.f;
  for (int k2 = f; k2 < 253; k2 += 64) bs += bwpart[k2];
  bs = wred_sum(bs);
  float bw = __shfl(bs, 0) * (1.f / (462.f * 4.f));  // /(n^2-n)/KMUL^(KNUM//2)
  float xx = l2buf[(size_t)(a * 22 + c) * 64 + f];
  float yy = l2buf[(size_t)((11 + a) * 22 + (11 + c)) * 64 + f];
  float xy = l2buf[(size_t)(a * 22 + (11 + c)) * 64 + f];
  float yx = l2buf[(size_t)((11 + a) * 22 + c) * 64 + f];
  float term = 0.f;
  float ib = 1.f / bw;
#pragma unroll
  for (int i = 0; i < 5; ++i) {
    term += expf(-xx * ib) + expf(-yy * ib) - expf(-xy * ib) - expf(-yx * ib);
    ib *= 0.5f;
  }
  float tt = wred_sum(term);
  if (f == 0) mmdpart[b] = tt;
}

// ---------------------------------------------------------------------------
// Kernel 5: finalize — triplet loss + variance + MMD mean -> out[0]
// ---------------------------------------------------------------------------
__global__ __launch_bounds__(64) void finalize_kernel(
    const float* __restrict__ dist, const float* __restrict__ mmdpart,
    float* __restrict__ out) {
  int lane = threadIdx.x;
  float lv_po = 0.f;
  float dg[5];
#pragma unroll
  for (int g = 0; g < 5; ++g) dg[g] = 0.f;
  if (lane < 8) {
    const float* dr = dist + lane * 15;
    float dn[10];
#pragma unroll
    for (int g = 0; g < 5; ++g) dg[g] = dr[g];
#pragma unroll
    for (int k = 0; k < 10; ++k) dn[k] = dr[5 + k];
    float s1 = 0.f, s2 = 0.f;
    int nz = 0;
#pragma unroll
    for (int g = 0; g < 5; ++g) {
#pragma unroll
      for (int k = 0; k < 5; ++k) {
        float v2 = dg[g] + 1.0f - dn[k];
        if (v2 > 0.f) { s1 += v2; ++nz; }
      }
#pragma unroll
      for (int k = 5; k < 10; ++k) {
        float v2 = dg[g] + 1.0f - dn[k];
        if (v2 > 0.f) { s2 += v2; ++nz; }
      }
    }
    float only_pos = (dg[0] + dg[1] + dg[2] + dg[3] + dg[4]) * 0.002f;
    float lv = (s1 * 0.7f + s2 * 0.3f) / (float)(nz + 1);
    lv_po = lv + only_pos;
  }
  float tl = wred_sum(lv_po);
  tl = __shfl(tl, 0);

  // two-pass ddof=1 variance over the 40 dg values
  float psum = dg[0] + dg[1] + dg[2] + dg[3] + dg[4];
  float tsum = wred_sum(psum);
  float mean = __shfl(tsum, 0) * (1.f / 40.f);
  float pdev = 0.f;
  if (lane < 8) {
#pragma unroll
    for (int g = 0; g < 5; ++g) {
      float dd = dg[g] - mean;
      pdev = fmaf(dd, dd, pdev);
    }
  }
  float tdev = wred_sum(pdev);
  tdev = __shfl(tdev, 0);

  float msum = 0.f;
  for (int k2 = lane; k2 < 121; k2 += 64) msum += mmdpart[k2];
  float mt = wred_sum(msum);

  if (lane == 0) {
    float total_loss = tl * (1.f / 8.f);
    float var_g = (tdev / 39.f) * 0.1f;
    float mmd = mt * (1.f / 7744.f);
    out[0] = total_loss + mmd + var_g;
  }
}

__global__ __launch_bounds__(64) void zero_out_kernel(float* __restrict__ out,
                                                      int n) {
  int i = blockIdx.x * 64 + threadIdx.x;
  if (i < n) out[i] = 0.f;
}

// ---------------------------------------------------------------------------
extern "C" void kernel_launch(void* const* d_in, const int* in_sizes, int n_in,
                              void* d_out, int out_size, void* d_ws,
                              size_t ws_size, hipStream_t stream) {
  const float* data = (const float*)d_in[0];
  const int* lens = (const int*)d_in[1];
  float* out = (float*)d_out;
  char* ws = (char*)d_ws;

  const size_t HDR = 131072;  // dist/bwpart/mmdpart/l2buf region
  const size_t per_pair = (size_t)NSK * T_ * sizeof(float);  // 1.31 MB

  // Strict workspace guard: never touch bytes beyond ws_size.
  if (ws_size < HDR + per_pair) {
    zero_out_kernel<<<dim3((out_size + 63) / 64), 64, 0, stream>>>(out,
                                                                   out_size);
    return;
  }

  float* dist = (float*)(ws + 0);        // 120 floats
  float* bwpart = (float*)(ws + 1024);   // 253 floats
  float* mmdpart = (float*)(ws + 3072);  // 121 floats
  float* l2buf = (float*)(ws + 4096);    // 22*22*64 floats = 123904 B
  float* wbuf = (float*)(ws + HDR);

  size_t avail = ws_size - HDR;
  int PC = (int)(avail / per_pair);
  if (PC > NPAIR) PC = NPAIR;

  for (int p0 = 0; p0 < NPAIR; p0 += PC) {
    int pc = (NPAIR - p0) < PC ? (NPAIR - p0) : PC;
    gemm_kernel<<<dim3(64, pc), 256, 0, stream>>>(data, wbuf, p0);
    dtw_kernel<<<dim3(pc), 64, 0, stream>>>(wbuf, lens, dist, p0);
  }
  mmd_l2_kernel<<<dim3(253), 64, 0, stream>>>(data, l2buf, bwpart);
  mmd_k_kernel<<<dim3(121), 64, 0, stream>>>(l2buf, bwpart, mmdpart);
  finalize_kernel<<<dim3(1), 64, 0, stream>>>(dist, mmdpart, out);
}

// Round 16
// 215.743 us; speedup vs baseline: 1.2657x; 1.0656x over previous
//
#include <hip/hip_runtime.h>
#include <hip/hip_bf16.h>
#include <cstdint>
#include <cstddef>

#define T_ 512
#define DF 64
#define NPAIR 120
#define STEPW 16
#define NEGS (-(1 << 26))
#define NSK 640   // skewed-W rows per pair (638 used, padded)

// softmin constants
#define C1_ 0.28853900817779268f   // log2(e)/5
#define C2D 3.4657359027997265     // 5*ln(2), double

__device__ __forceinline__ float wred_sum(float v) {
#pragma unroll
  for (int o = 32; o > 0; o >>= 1) v += __shfl_down(v, o);
  return v;  // lane 0 holds the total
}

__device__ __forceinline__ int dexp(double x) {
  // biased-exponent field - 1023; 0.0 -> -1023 (safe "very small" marker)
  return (int)((__double_as_longlong(x) >> 52) & 0x7ff) - 1023;
}

// unsinkable 16B global load to a named VGPR quad (HK pattern). Data is NOT
// valid until a manual s_waitcnt vmcnt(N); rule-18: sched_barrier after wait.
#define GLOAD(DST, PTR)                                                    \
  asm volatile("global_load_dwordx4 %0, %1, off"                           \
               : "=&v"(DST) : "v"(PTR) : "memory")

// ---------------------------------------------------------------------------
// Kernel 1: pairwise sq-dist GEMM; epilogue stores W = exp(-D/gamma) in
// STAGGER-SKEWED (2 rows/lane) + WITHIN-ROW-PERMUTED layout (r13-verified).
// r16: LDS staged TRANSPOSED (XsT[k][r], row stride 68 = 16B-aligned) so the
// k-loop reads fragments with TWO ds_read_b128 per k instead of 8 scalar
// ds_read_b32 (r15 post-mortem: gemm was LDS-issue-bound at ~85 us, 2x its
// ~45 us roofline; 512 scalar LDS reads/thread were the cost).
// ---------------------------------------------------------------------------
__global__ __launch_bounds__(256) void gemm_kernel(
    const float* __restrict__ data, float* __restrict__ wbuf, int pair0) {
  __shared__ float XsT[64][68];  // XsT[k][r] = X[i0+r][k]; 68: %4==0, %32==4
  __shared__ float YsT[64][68];  // YsT[k][r] = Y[j0+r][k]
  __shared__ float nrmx[64];
  __shared__ float nrmy[64];

  const int tile = blockIdx.x;   // 0..63 = (bi<<3)|bj
  const int pc = blockIdx.y;     // pair within chunk
  const int p = pair0 + pc;
  const int w = p / 15;
  const int o = p - w * 15;
  const int aidx = w * STEPW;
  const int oidx = aidx + 1 + o;
  const int i0 = (tile >> 3) << 6;
  const int j0 = (tile & 7) << 6;
  const int tid = threadIdx.x;

  const float* Xg = data + (size_t)aidx * (T_ * DF);
  const float* Yg = data + (size_t)oidx * (T_ * DF);

  // stage transposed: coalesced global float4 reads, scattered LDS writes
#pragma unroll
  for (int l = 0; l < 4; ++l) {
    int idx = tid + l * 256;  // 0..1023
    int r = idx >> 4;
    int c = idx & 15;
    float4 xv = reinterpret_cast<const float4*>(Xg + (size_t)(i0 + r) * DF)[c];
    float4 yv = reinterpret_cast<const float4*>(Yg + (size_t)(j0 + r) * DF)[c];
    XsT[4 * c + 0][r] = xv.x; XsT[4 * c + 1][r] = xv.y;
    XsT[4 * c + 2][r] = xv.z; XsT[4 * c + 3][r] = xv.w;
    YsT[4 * c + 0][r] = yv.x; YsT[4 * c + 1][r] = yv.y;
    YsT[4 * c + 2][r] = yv.z; YsT[4 * c + 3][r] = yv.w;
  }
  __syncthreads();

  if (tid < 128) {
    int r = tid & 63;
    float s = 0.f;
    if (tid < 64) {
#pragma unroll
      for (int k = 0; k < 64; ++k) s = fmaf(XsT[k][r], XsT[k][r], s);
      nrmx[r] = s;
    } else {
#pragma unroll
      for (int k = 0; k < 64; ++k) s = fmaf(YsT[k][r], YsT[k][r], s);
      nrmy[r] = s;
    }
  }
  __syncthreads();

  const int tx = tid & 15;
  const int ty = tid >> 4;
  float acc[4][4];
#pragma unroll
  for (int a = 0; a < 4; ++a)
#pragma unroll
    for (int b = 0; b < 4; ++b) acc[a][b] = 0.f;

#pragma unroll 4
  for (int k = 0; k < 64; ++k) {
    float4 xr = *reinterpret_cast<const float4*>(&XsT[k][ty * 4]);
    float4 yr = *reinterpret_cast<const float4*>(&YsT[k][tx * 4]);
    const float xa[4] = {xr.x, xr.y, xr.z, xr.w};
    const float yb[4] = {yr.x, yr.y, yr.z, yr.w};
#pragma unroll
    for (int a = 0; a < 4; ++a)
#pragma unroll
      for (int b = 0; b < 4; ++b) acc[a][b] = fmaf(xa[a], yb[b], acc[a][b]);
  }

  // epilogue: my float4 (cols j0+4tx..+3) belongs to lane g8 = (j0>>3)+(tx>>1)
  const int g8 = (j0 >> 3) + (tx >> 1);
  const int off = ((tx & 1) << 8) + 4 * g8;
  float* Wp = wbuf + (size_t)pc * (NSK * T_) + off;
#pragma unroll
  for (int a = 0; a < 4; ++a) {
    int ii = ty * 4 + a;
    float nx = nrmx[ii];
    float4 v;
    v.x = __builtin_exp2f(-(nx + nrmy[tx * 4 + 0] - 2.f * acc[a][0]) * C1_);
    v.y = __builtin_exp2f(-(nx + nrmy[tx * 4 + 1] - 2.f * acc[a][1]) * C1_);
    v.z = __builtin_exp2f(-(nx + nrmy[tx * 4 + 2] - 2.f * acc[a][2]) * C1_);
    v.w = __builtin_exp2f(-(nx + nrmy[tx * 4 + 3] - 2.f * acc[a][3]) * C1_);
    *reinterpret_cast<float4*>(Wp + (size_t)(i0 + ii + 2 * g8) * T_) = v;
  }
}

// ---------------------------------------------------------------------------
// Kernel 2: softDTW, exp-domain fp64 + block exponent, 2 rows/superstep,
// r13 geometry, W staged DIRECTLY IN REGISTERS (r15-verified: 132->112 us):
// 12 named float4-pair row slots, modulo-scheduled (unroll 6), asm-volatile
// global_load_dwordx4 (unsinkable), hand-counted s_waitcnt vmcnt(12).
// BYTE-IDENTICAL to round 15 (isolates the gemm change).
// ---------------------------------------------------------------------------
__global__ __launch_bounds__(64) void dtw_kernel(
    const float* __restrict__ Wm, const int* __restrict__ lens,
    float* __restrict__ dist, int pair0) {
  const int pc = blockIdx.x;
  const int p = pair0 + pc;
  const int w = p / 15;
  const int o = p - w * 15;
  const int lx = lens[w * STEPW];
  const int ly = lens[w * STEPW + 1 + o];
  const int l = threadIdx.x;
  const int imax = lx - 1;
  const int jt = ly - 1;
  const int lt = jt >> 3, ct = jt & 7;
  const int M = lt + (imax >> 1);  // last superstep needed by lane lt
  const float invl = 1.f / (float)(lx + ly);

  const float* wp = Wm + (size_t)pc * (NSK * T_) + 4 * l;

  // 12 row slots, 2 float4 each (96 VGPRs): row R -> slot R%12
  float4 K0a, K0b, K1a, K1b, K2a, K2b, K3a, K3b;
  float4 K4a, K4b, K5a, K5b, K6a, K6b, K7a, K7b;
  float4 K8a, K8b, K9a, K9b, K10a, K10b, K11a, K11b;

#define LDROW(A, B, R)                                     \
  {                                                        \
    int r_ = (R); r_ = r_ > 637 ? 637 : r_;                \
    const float* p_ = wp + (size_t)r_ * T_;                \
    GLOAD(A, p_); GLOAD(B, p_ + 256);                      \
  }

  // prologue: rows 0..5 in flight (12 loads)
  LDROW(K0a, K0b, 0); LDROW(K1a, K1b, 1);
  LDROW(K2a, K2b, 2); LDROW(K3a, K3b, 3);
  LDROW(K4a, K4b, 4); LDROW(K5a, K5b, 5);

  // committed-row E (fp64 mantissas, shared block exponent S)
  double e0 = 0., e1 = 0., e2 = 0., e3 = 0.;
  double e4 = 0., e5 = 0., e6 = 0., e7 = 0.;
  double e7A = 0.;            // row-A e7 of current committed pair
  int S = NEGS;
  double pvB = 0.;  int psB = NEGS;  // 1-superstep-delayed neighbor row-B

#define SUP(MM, SA0, SA1, SB0, SB1, RA0, RA1, RB0, RB1)                    \
  {                                                                        \
    const int m_ = (MM);                                                   \
    double nvA = __shfl_up(e7A, 1);                                        \
    double nvB = __shfl_up(e7, 1);                                         \
    int ns = __shfl_up(S, 1);                                              \
    LDROW(RA0, RA1, 2 * m_ + 6);                                           \
    LDROW(RB0, RB1, 2 * m_ + 7);                                           \
    asm volatile("s_waitcnt vmcnt(12)" ::: "memory");                      \
    __builtin_amdgcn_sched_barrier(0);                                     \
    const int i = 2 * (m_ - l);                                            \
    double lA = nvA, dA = pvB, lB = nvB, dB2 = nvA;                        \
    int slA = ns, sdA = psB, slB = ns, sdB = ns;                           \
    if (l == 0) {                                                          \
      lA = 0.; slA = NEGS;                                                 \
      dA = (i == 0) ? 1. : 0.; sdA = (i == 0) ? 0 : NEGS;                  \
      lB = 0.; slB = NEGS;                                                 \
      dB2 = 0.; sdB = NEGS;                                                \
    }                                                                      \
    if ((unsigned)i <= (unsigned)imax) {                                   \
      double sum = ((e0 + e1) + (e2 + e3)) + ((e4 + e5) + (e6 + e7));      \
      int NA = max(S + dexp(sum), max(slA + dexp(lA), sdA + dexp(dA)));    \
      const int dS = S - NA;                                               \
      if (dS != 0) {                                                       \
        e0 = ldexp(e0, dS); e1 = ldexp(e1, dS);                            \
        e2 = ldexp(e2, dS); e3 = ldexp(e3, dS);                            \
        e4 = ldexp(e4, dS); e5 = ldexp(e5, dS);                            \
        e6 = ldexp(e6, dS); e7 = ldexp(e7, dS);                            \
      }                                                                    \
      double L = ldexp(lA, slA - NA);                                      \
      double G = ldexp(dA, sdA - NA);                                      \
      const double WA0 = (double)SA0.x, WA1 = (double)SA0.y;               \
      const double WA2 = (double)SA0.z, WA3 = (double)SA0.w;               \
      const double WA4 = (double)SA1.x, WA5 = (double)SA1.y;               \
      const double WA6 = (double)SA1.z, WA7 = (double)SA1.w;               \
      double qa0 = WA0 * ((L + G) + e0);                                   \
      double qa1 = WA1 * (e1 + e0);                                        \
      double qa2 = WA2 * (e2 + e1);                                        \
      double qa3 = WA3 * (e3 + e2);                                        \
      double qa4 = WA4 * (e4 + e3);                                        \
      double qa5 = WA5 * (e5 + e4);                                        \
      double qa6 = WA6 * (e6 + e5);                                        \
      double qa7 = WA7 * (e7 + e6);                                        \
      double a0 = qa0;                                                     \
      double a1 = fma(WA1, a0, qa1);                                       \
      double a2 = fma(WA2, a1, qa2);                                       \
      double a3 = fma(WA3, a2, qa3);                                       \
      double a4 = fma(WA4, a3, qa4);                                       \
      double a5 = fma(WA5, a4, qa5);                                       \
      double a6 = fma(WA6, a5, qa6);                                       \
      double a7 = fma(WA7, a6, qa7);                                       \
      if (i + 1 <= imax) {                                                 \
        int NB = max(NA, max(slB + dexp(lB), sdB + dexp(dB2)));            \
        const int dB = NA - NB;                                            \
        if (dB != 0) {                                                     \
          a0 = ldexp(a0, dB); a1 = ldexp(a1, dB);                          \
          a2 = ldexp(a2, dB); a3 = ldexp(a3, dB);                          \
          a4 = ldexp(a4, dB); a5 = ldexp(a5, dB);                          \
          a6 = ldexp(a6, dB); a7 = ldexp(a7, dB);                          \
        }                                                                  \
        double LB = ldexp(lB, slB - NB);                                   \
        double GB = ldexp(dB2, sdB - NB);                                  \
        const double WB0 = (double)SB0.x, WB1 = (double)SB0.y;             \
        const double WB2 = (double)SB0.z, WB3 = (double)SB0.w;             \
        const double WB4 = (double)SB1.x, WB5 = (double)SB1.y;             \
        const double WB6 = (double)SB1.z, WB7 = (double)SB1.w;             \
        double qb0 = WB0 * ((LB + GB) + a0);                               \
        double qb1 = WB1 * (a1 + a0);                                      \
        double qb2 = WB2 * (a2 + a1);                                      \
        double qb3 = WB3 * (a3 + a2);                                      \
        double qb4 = WB4 * (a4 + a3);                                      \
        double qb5 = WB5 * (a5 + a4);                                      \
        double qb6 = WB6 * (a6 + a5);                                      \
        double qb7 = WB7 * (a7 + a6);                                      \
        e0 = qb0;                                                          \
        e1 = fma(WB1, e0, qb1);                                            \
        e2 = fma(WB2, e1, qb2);                                            \
        e3 = fma(WB3, e2, qb3);                                            \
        e4 = fma(WB4, e3, qb4);                                            \
        e5 = fma(WB5, e4, qb5);                                            \
        e6 = fma(WB6, e5, qb6);                                            \
        e7 = fma(WB7, e6, qb7);                                            \
        e7A = a7;  /* already aligned to NB */                             \
        S = NB;                                                            \
      } else {                                                             \
        e0 = a0; e1 = a1; e2 = a2; e3 = a3;                                \
        e4 = a4; e5 = a5; e6 = a6; e7 = a7;                                \
        e7A = a7;                                                          \
        S = NA;                                                            \
      }                                                                    \
    }                                                                      \
    pvB = nvB; psB = ns;                                                   \
  }

  const int nsup = (M + 6) / 6 * 6;  // covers m = 0..M
  for (int mb = 0; mb < nsup; mb += 6) {
    SUP(mb + 0, K0a, K0b, K1a, K1b, K6a, K6b, K7a, K7b);
    SUP(mb + 1, K2a, K2b, K3a, K3b, K8a, K8b, K9a, K9b);
    SUP(mb + 2, K4a, K4b, K5a, K5b, K10a, K10b, K11a, K11b);
    SUP(mb + 3, K6a, K6b, K7a, K7b, K0a, K0b, K1a, K1b);
    SUP(mb + 4, K8a, K8b, K9a, K9b, K2a, K2b, K3a, K3b);
    SUP(mb + 5, K10a, K10b, K11a, K11b, K4a, K4b, K5a, K5b);
  }

  // drain all outstanding loads before the store (vmcnt counts stores too)
  asm volatile("s_waitcnt vmcnt(0)" ::: "memory");

  if (l == lt) {
    double out_v = (ct == 0) ? e0 : (ct == 1) ? e1 : (ct == 2) ? e2
                 : (ct == 3) ? e3 : (ct == 4) ? e4 : (ct == 5) ? e5
                 : (ct == 6) ? e6 : e7;
    double vv = (out_v > 0.) ? out_v : 1e-300;  // belt-and-braces
    double r = -C2D * (log2(vv) + (double)S);
    dist[p] = (float)(r * (double)invl);
  }
}

// ---------------------------------------------------------------------------
// Kernel 3: MMD pairwise per-feature L2 (upper triangle, mirrored)
// ---------------------------------------------------------------------------
__global__ __launch_bounds__(64) void mmd_l2_kernel(
    const float* __restrict__ data, float* __restrict__ l2buf,
    float* __restrict__ bwpart) {
  int b = blockIdx.x;  // 0..252 upper-tri (incl diag) index
  int u = 0, rem = b;
  while (rem >= 22 - u) { rem -= 22 - u; ++u; }
  int v = u + rem;
  int f = threadIdx.x;
  float s = 0.f;
  if (u != v) {
    int iu = u < 11 ? u : u + 5;
    int iv = v < 11 ? v : v + 5;
    const float* A = data + (size_t)iu * (T_ * DF) + f;
    const float* B = data + (size_t)iv * (T_ * DF) + f;
#pragma unroll 8
    for (int t = 0; t < T_; ++t) {
      float dd = A[(size_t)t * DF] - B[(size_t)t * DF];
      s = fmaf(dd, dd, s);
    }
  }
  l2buf[(size_t)(u * 22 + v) * 64 + f] = s;
  l2buf[(size_t)(v * 22 + u) * 64 + f] = s;
  float tot = wred_sum(s);
  if (f == 0) bwpart[b] = 2.f * tot;  // diag contributes exactly 0
}

// ---------------------------------------------------------------------------
// Kernel 4: MMD kernel sums per (a,c) of the 11x11 grid
// ---------------------------------------------------------------------------
__global__ __launch_bounds__(64) void mmd_k_kernel(
    const float* __restrict__ l2buf, const float* __restrict__ bwpart,
    float* __restrict__ mmdpart) {
  int b = blockIdx.x;  // 0..120
  int a = b / 11, c = b - a * 11;
  int f = threadIdx.x;
  float bs = 0.f;
  for (int k2 = f; k2 < 253; k2 += 64) bs += bwpart[k2];
  bs = wred_sum(bs);
  float bw = __shfl(bs, 0) * (1.f / (462.f * 4.f));  // /(n^2-n)/KMUL^(KNUM//2)
  float xx = l2buf[(size_t)(a * 22 + c) * 64 + f];
  float yy = l2buf[(size_t)((11 + a) * 22 + (11 + c)) * 64 + f];
  float xy = l2buf[(size_t)(a * 22 + (11 + c)) * 64 + f];
  float yx = l2buf[(size_t)((11 + a) * 22 + c) * 64 + f];
  float term = 0.f;
  float ib = 1.f / bw;
#pragma unroll
  for (int i = 0; i < 5; ++i) {
    term += expf(-xx * ib) + expf(-yy * ib) - expf(-xy * ib) - expf(-yx * ib);
    ib *= 0.5f;
  }
  float tt = wred_sum(term);
  if (f == 0) mmdpart[b] = tt;
}

// ---------------------------------------------------------------------------
// Kernel 5: finalize — triplet loss + variance + MMD mean -> out[0]
// ---------------------------------------------------------------------------
__global__ __launch_bounds__(64) void finalize_kernel(
    const float* __restrict__ dist, const float* __restrict__ mmdpart,
    float* __restrict__ out) {
  int lane = threadIdx.x;
  float lv_po = 0.f;
  float dg[5];
#pragma unroll
  for (int g = 0; g < 5; ++g) dg[g] = 0.f;
  if (lane < 8) {
    const float* dr = dist + lane * 15;
    float dn[10];
#pragma unroll
    for (int g = 0; g < 5; ++g) dg[g] = dr[g];
#pragma unroll
    for (int k = 0; k < 10; ++k) dn[k] = dr[5 + k];
    float s1 = 0.f, s2 = 0.f;
    int nz = 0;
#pragma unroll
    for (int g = 0; g < 5; ++g) {
#pragma unroll
      for (int k = 0; k < 5; ++k) {
        float v2 = dg[g] + 1.0f - dn[k];
        if (v2 > 0.f) { s1 += v2; ++nz; }
      }
#pragma unroll
      for (int k = 5; k < 10; ++k) {
        float v2 = dg[g] + 1.0f - dn[k];
        if (v2 > 0.f) { s2 += v2; ++nz; }
      }
    }
    float only_pos = (dg[0] + dg[1] + dg[2] + dg[3] + dg[4]) * 0.002f;
    float lv = (s1 * 0.7f + s2 * 0.3f) / (float)(nz + 1);
    lv_po = lv + only_pos;
  }
  float tl = wred_sum(lv_po);
  tl = __shfl(tl, 0);

  // two-pass ddof=1 variance over the 40 dg values
  float psum = dg[0] + dg[1] + dg[2] + dg[3] + dg[4];
  float tsum = wred_sum(psum);
  float mean = __shfl(tsum, 0) * (1.f / 40.f);
  float pdev = 0.f;
  if (lane < 8) {
#pragma unroll
    for (int g = 0; g < 5; ++g) {
      float dd = dg[g] - mean;
      pdev = fmaf(dd, dd, pdev);
    }
  }
  float tdev = wred_sum(pdev);
  tdev = __shfl(tdev, 0);

  float msum = 0.f;
  for (int k2 = lane; k2 < 121; k2 += 64) msum += mmdpart[k2];
  float mt = wred_sum(msum);

  if (lane == 0) {
    float total_loss = tl * (1.f / 8.f);
    float var_g = (tdev / 39.f) * 0.1f;
    float mmd = mt * (1.f / 7744.f);
    out[0] = total_loss + mmd + var_g;
  }
}

__global__ __launch_bounds__(64) void zero_out_kernel(float* __restrict__ out,
                                                      int n) {
  int i = blockIdx.x * 64 + threadIdx.x;
  if (i < n) out[i] = 0.f;
}

// ---------------------------------------------------------------------------
extern "C" void kernel_launch(void* const* d_in, const int* in_sizes, int n_in,
                              void* d_out, int out_size, void* d_ws,
                              size_t ws_size, hipStream_t stream) {
  const float* data = (const float*)d_in[0];
  const int* lens = (const int*)d_in[1];
  float* out = (float*)d_out;
  char* ws = (char*)d_ws;

  const size_t HDR = 131072;  // dist/bwpart/mmdpart/l2buf region
  const size_t per_pair = (size_t)NSK * T_ * sizeof(float);  // 1.31 MB

  // Strict workspace guard: never touch bytes beyond ws_size.
  if (ws_size < HDR + per_pair) {
    zero_out_kernel<<<dim3((out_size + 63) / 64), 64, 0, stream>>>(out,
                                                                   out_size);
    return;
  }

  float* dist = (float*)(ws + 0);        // 120 floats
  float* bwpart = (float*)(ws + 1024);   // 253 floats
  float* mmdpart = (float*)(ws + 3072);  // 121 floats
  float* l2buf = (float*)(ws + 4096);    // 22*22*64 floats = 123904 B
  float* wbuf = (float*)(ws + HDR);

  size_t avail = ws_size - HDR;
  int PC = (int)(avail / per_pair);
  if (PC > NPAIR) PC = NPAIR;

  for (int p0 = 0; p0 < NPAIR; p0 += PC) {
    int pc = (NPAIR - p0) < PC ? (NPAIR - p0) : PC;
    gemm_kernel<<<dim3(64, pc), 256, 0, stream>>>(data, wbuf, p0);
    dtw_kernel<<<dim3(pc), 64, 0, stream>>>(wbuf, lens, dist, p0);
  }
  mmd_l2_kernel<<<dim3(253), 64, 0, stream>>>(data, l2buf, bwpart);
  mmd_k_kernel<<<dim3(121), 64, 0, stream>>>(l2buf, bwpart, mmdpart);
  finalize_kernel<<<dim3(1), 64, 0, stream>>>(dist, mmdpart, out);
}

// Round 17
// 208.222 us; speedup vs baseline: 1.3114x; 1.0361x over previous
//
#include <hip/hip_runtime.h>
#include <hip/hip_bf16.h>
#include <cstdint>
#include <cstddef>

#define T_ 512
#define DF 64
#define NPAIR 120
#define STEPW 16
#define NEGS (-(1 << 26))
#define NSK 640   // skewed-W rows per pair (638 used, padded)

// softmin constants
#define C1_ 0.28853900817779268f   // log2(e)/5
#define C2D 3.4657359027997265     // 5*ln(2), double

__device__ __forceinline__ float wred_sum(float v) {
#pragma unroll
  for (int o = 32; o > 0; o >>= 1) v += __shfl_down(v, o);
  return v;  // lane 0 holds the total
}

__device__ __forceinline__ int dexp(double x) {
  // biased-exponent field - 1023; 0.0 -> -1023 (safe "very small" marker)
  return (int)((__double_as_longlong(x) >> 52) & 0x7ff) - 1023;
}

// unsinkable 16B global load to a named VGPR quad (HK pattern). Data is NOT
// valid until a manual s_waitcnt vmcnt(N); rule-18: sched_barrier after wait.
#define GLOAD(DST, PTR)                                                    \
  asm volatile("global_load_dwordx4 %0, %1, off"                           \
               : "=&v"(DST) : "v"(PTR) : "memory")

// ---------------------------------------------------------------------------
// Kernel 1 (FUSED): gemm for blockIdx.y < npc; mmd_l2 for blockIdx.y == npc
// (only launched with the extra row on the first chunk). gemm part is
// byte-identical to r16 (XsT transposed staging, 2x ds_read_b128/k).
// mmd_l2: 4 upper-tri pairs per 256-thread block (one per 64-lane wave).
// ---------------------------------------------------------------------------
__global__ __launch_bounds__(256) void gemm_mmd_kernel(
    const float* __restrict__ data, float* __restrict__ wbuf, int pair0,
    int npc, float* __restrict__ l2buf, float* __restrict__ bwpart) {
  if ((int)blockIdx.y == npc) {
    // ---- mmd_l2 path: wave g handles tri-pair b = blockIdx.x*4 + g
    const int tid = threadIdx.x;
    const int g = tid >> 6;
    const int f = tid & 63;
    const int b = (int)blockIdx.x * 4 + g;
    if (b < 253) {
      int u = 0, rem = b;
      while (rem >= 22 - u) { rem -= 22 - u; ++u; }
      int v = u + rem;
      float s = 0.f;
      if (u != v) {
        int iu = u < 11 ? u : u + 5;
        int iv = v < 11 ? v : v + 5;
        const float* A = data + (size_t)iu * (T_ * DF) + f;
        const float* B = data + (size_t)iv * (T_ * DF) + f;
#pragma unroll 8
        for (int t = 0; t < T_; ++t) {
          float dd = A[(size_t)t * DF] - B[(size_t)t * DF];
          s = fmaf(dd, dd, s);
        }
      }
      l2buf[(size_t)(u * 22 + v) * 64 + f] = s;
      l2buf[(size_t)(v * 22 + u) * 64 + f] = s;
      float tot = wred_sum(s);
      if (f == 0) bwpart[b] = 2.f * tot;  // diag contributes exactly 0
    }
    return;
  }

  // ---- gemm path (byte-identical math to r16)
  __shared__ float XsT[64][68];  // XsT[k][r] = X[i0+r][k]; 68: %4==0, %32==4
  __shared__ float YsT[64][68];  // YsT[k][r] = Y[j0+r][k]
  __shared__ float nrmx[64];
  __shared__ float nrmy[64];

  const int tile = blockIdx.x;   // 0..63 = (bi<<3)|bj
  const int pc = blockIdx.y;     // pair within chunk
  const int p = pair0 + pc;
  const int w = p / 15;
  const int o = p - w * 15;
  const int aidx = w * STEPW;
  const int oidx = aidx + 1 + o;
  const int i0 = (tile >> 3) << 6;
  const int j0 = (tile & 7) << 6;
  const int tid = threadIdx.x;

  const float* Xg = data + (size_t)aidx * (T_ * DF);
  const float* Yg = data + (size_t)oidx * (T_ * DF);

  // stage transposed: coalesced global float4 reads, scattered LDS writes
#pragma unroll
  for (int l = 0; l < 4; ++l) {
    int idx = tid + l * 256;  // 0..1023
    int r = idx >> 4;
    int c = idx & 15;
    float4 xv = reinterpret_cast<const float4*>(Xg + (size_t)(i0 + r) * DF)[c];
    float4 yv = reinterpret_cast<const float4*>(Yg + (size_t)(j0 + r) * DF)[c];
    XsT[4 * c + 0][r] = xv.x; XsT[4 * c + 1][r] = xv.y;
    XsT[4 * c + 2][r] = xv.z; XsT[4 * c + 3][r] = xv.w;
    YsT[4 * c + 0][r] = yv.x; YsT[4 * c + 1][r] = yv.y;
    YsT[4 * c + 2][r] = yv.z; YsT[4 * c + 3][r] = yv.w;
  }
  __syncthreads();

  if (tid < 128) {
    int r = tid & 63;
    float s = 0.f;
    if (tid < 64) {
#pragma unroll
      for (int k = 0; k < 64; ++k) s = fmaf(XsT[k][r], XsT[k][r], s);
      nrmx[r] = s;
    } else {
#pragma unroll
      for (int k = 0; k < 64; ++k) s = fmaf(YsT[k][r], YsT[k][r], s);
      nrmy[r] = s;
    }
  }
  __syncthreads();

  const int tx = tid & 15;
  const int ty = tid >> 4;
  float acc[4][4];
#pragma unroll
  for (int a = 0; a < 4; ++a)
#pragma unroll
    for (int b = 0; b < 4; ++b) acc[a][b] = 0.f;

#pragma unroll 4
  for (int k = 0; k < 64; ++k) {
    float4 xr = *reinterpret_cast<const float4*>(&XsT[k][ty * 4]);
    float4 yr = *reinterpret_cast<const float4*>(&YsT[k][tx * 4]);
    const float xa[4] = {xr.x, xr.y, xr.z, xr.w};
    const float yb[4] = {yr.x, yr.y, yr.z, yr.w};
#pragma unroll
    for (int a = 0; a < 4; ++a)
#pragma unroll
      for (int b = 0; b < 4; ++b) acc[a][b] = fmaf(xa[a], yb[b], acc[a][b]);
  }

  // epilogue: my float4 (cols j0+4tx..+3) belongs to lane g8 = (j0>>3)+(tx>>1)
  const int g8 = (j0 >> 3) + (tx >> 1);
  const int off = ((tx & 1) << 8) + 4 * g8;
  float* Wp = wbuf + (size_t)pc * (NSK * T_) + off;
#pragma unroll
  for (int a = 0; a < 4; ++a) {
    int ii = ty * 4 + a;
    float nx = nrmx[ii];
    float4 v;
    v.x = __builtin_exp2f(-(nx + nrmy[tx * 4 + 0] - 2.f * acc[a][0]) * C1_);
    v.y = __builtin_exp2f(-(nx + nrmy[tx * 4 + 1] - 2.f * acc[a][1]) * C1_);
    v.z = __builtin_exp2f(-(nx + nrmy[tx * 4 + 2] - 2.f * acc[a][2]) * C1_);
    v.w = __builtin_exp2f(-(nx + nrmy[tx * 4 + 3] - 2.f * acc[a][3]) * C1_);
    *reinterpret_cast<float4*>(Wp + (size_t)(i0 + ii + 2 * g8) * T_) = v;
  }
}

// ---------------------------------------------------------------------------
// Kernel 2 (FUSED): dtw for blockIdx.x < npc; mmd_k for blockIdx.x >= npc
// (121 extra blocks on the first chunk — they run on CUs dtw leaves idle).
// dtw part byte-identical to r15/r16 (register-staged W, vmcnt(12)).
// ---------------------------------------------------------------------------
__global__ __launch_bounds__(64) void dtw_mmdk_kernel(
    const float* __restrict__ Wm, const int* __restrict__ lens,
    float* __restrict__ dist, int pair0, int npc,
    const float* __restrict__ l2buf, const float* __restrict__ bwpart,
    float* __restrict__ mmdpart) {
  if ((int)blockIdx.x >= npc) {
    // ---- mmd_k path
    int b = (int)blockIdx.x - npc;  // 0..120
    if (b < 121) {
      int a = b / 11, c = b - a * 11;
      int f = threadIdx.x;
      float bs = 0.f;
      for (int k2 = f; k2 < 253; k2 += 64) bs += bwpart[k2];
      bs = wred_sum(bs);
      float bw = __shfl(bs, 0) * (1.f / (462.f * 4.f));
      float xx = l2buf[(size_t)(a * 22 + c) * 64 + f];
      float yy = l2buf[(size_t)((11 + a) * 22 + (11 + c)) * 64 + f];
      float xy = l2buf[(size_t)(a * 22 + (11 + c)) * 64 + f];
      float yx = l2buf[(size_t)((11 + a) * 22 + c) * 64 + f];
      float term = 0.f;
      float ib = 1.f / bw;
#pragma unroll
      for (int i = 0; i < 5; ++i) {
        term += expf(-xx * ib) + expf(-yy * ib) - expf(-xy * ib)
              - expf(-yx * ib);
        ib *= 0.5f;
      }
      float tt = wred_sum(term);
      if (f == 0) mmdpart[b] = tt;
    }
    return;
  }

  const int pc = blockIdx.x;
  const int p = pair0 + pc;
  const int w = p / 15;
  const int o = p - w * 15;
  const int lx = lens[w * STEPW];
  const int ly = lens[w * STEPW + 1 + o];
  const int l = threadIdx.x;
  const int imax = lx - 1;
  const int jt = ly - 1;
  const int lt = jt >> 3, ct = jt & 7;
  const int M = lt + (imax >> 1);  // last superstep needed by lane lt
  const float invl = 1.f / (float)(lx + ly);

  const float* wp = Wm + (size_t)pc * (NSK * T_) + 4 * l;

  // 12 row slots, 2 float4 each (96 VGPRs): row R -> slot R%12
  float4 K0a, K0b, K1a, K1b, K2a, K2b, K3a, K3b;
  float4 K4a, K4b, K5a, K5b, K6a, K6b, K7a, K7b;
  float4 K8a, K8b, K9a, K9b, K10a, K10b, K11a, K11b;

#define LDROW(A, B, R)                                     \
  {                                                        \
    int r_ = (R); r_ = r_ > 637 ? 637 : r_;                \
    const float* p_ = wp + (size_t)r_ * T_;                \
    GLOAD(A, p_); GLOAD(B, p_ + 256);                      \
  }

  // prologue: rows 0..5 in flight (12 loads)
  LDROW(K0a, K0b, 0); LDROW(K1a, K1b, 1);
  LDROW(K2a, K2b, 2); LDROW(K3a, K3b, 3);
  LDROW(K4a, K4b, 4); LDROW(K5a, K5b, 5);

  // committed-row E (fp64 mantissas, shared block exponent S)
  double e0 = 0., e1 = 0., e2 = 0., e3 = 0.;
  double e4 = 0., e5 = 0., e6 = 0., e7 = 0.;
  double e7A = 0.;            // row-A e7 of current committed pair
  int S = NEGS;
  double pvB = 0.;  int psB = NEGS;  // 1-superstep-delayed neighbor row-B

#define SUP(MM, SA0, SA1, SB0, SB1, RA0, RA1, RB0, RB1)                    \
  {                                                                        \
    const int m_ = (MM);                                                   \
    double nvA = __shfl_up(e7A, 1);                                        \
    double nvB = __shfl_up(e7, 1);                                         \
    int ns = __shfl_up(S, 1);                                              \
    LDROW(RA0, RA1, 2 * m_ + 6);                                           \
    LDROW(RB0, RB1, 2 * m_ + 7);                                           \
    asm volatile("s_waitcnt vmcnt(12)" ::: "memory");                      \
    __builtin_amdgcn_sched_barrier(0);                                     \
    const int i = 2 * (m_ - l);                                            \
    double lA = nvA, dA = pvB, lB = nvB, dB2 = nvA;                        \
    int slA = ns, sdA = psB, slB = ns, sdB = ns;                           \
    if (l == 0) {                                                          \
      lA = 0.; slA = NEGS;                                                 \
      dA = (i == 0) ? 1. : 0.; sdA = (i == 0) ? 0 : NEGS;                  \
      lB = 0.; slB = NEGS;                                                 \
      dB2 = 0.; sdB = NEGS;                                                \
    }                                                                      \
    if ((unsigned)i <= (unsigned)imax) {                                   \
      double sum = ((e0 + e1) + (e2 + e3)) + ((e4 + e5) + (e6 + e7));      \
      int NA = max(S + dexp(sum), max(slA + dexp(lA), sdA + dexp(dA)));    \
      const int dS = S - NA;                                               \
      if (dS != 0) {                                                       \
        e0 = ldexp(e0, dS); e1 = ldexp(e1, dS);                            \
        e2 = ldexp(e2, dS); e3 = ldexp(e3, dS);                            \
        e4 = ldexp(e4, dS); e5 = ldexp(e5, dS);                            \
        e6 = ldexp(e6, dS); e7 = ldexp(e7, dS);                            \
      }                                                                    \
      double L = ldexp(lA, slA - NA);                                      \
      double G = ldexp(dA, sdA - NA);                                      \
      const double WA0 = (double)SA0.x, WA1 = (double)SA0.y;               \
      const double WA2 = (double)SA0.z, WA3 = (double)SA0.w;               \
      const double WA4 = (double)SA1.x, WA5 = (double)SA1.y;               \
      const double WA6 = (double)SA1.z, WA7 = (double)SA1.w;               \
      double qa0 = WA0 * ((L + G) + e0);                                   \
      double qa1 = WA1 * (e1 + e0);                                        \
      double qa2 = WA2 * (e2 + e1);                                        \
      double qa3 = WA3 * (e3 + e2);                                        \
      double qa4 = WA4 * (e4 + e3);                                        \
      double qa5 = WA5 * (e5 + e4);                                        \
      double qa6 = WA6 * (e6 + e5);                                        \
      double qa7 = WA7 * (e7 + e6);                                        \
      double a0 = qa0;                                                     \
      double a1 = fma(WA1, a0, qa1);                                       \
      double a2 = fma(WA2, a1, qa2);                                       \
      double a3 = fma(WA3, a2, qa3);                                       \
      double a4 = fma(WA4, a3, qa4);                                       \
      double a5 = fma(WA5, a4, qa5);                                       \
      double a6 = fma(WA6, a5, qa6);                                       \
      double a7 = fma(WA7, a6, qa7);                                       \
      if (i + 1 <= imax) {                                                 \
        int NB = max(NA, max(slB + dexp(lB), sdB + dexp(dB2)));            \
        const int dB = NA - NB;                                            \
        if (dB != 0) {                                                     \
          a0 = ldexp(a0, dB); a1 = ldexp(a1, dB);                          \
          a2 = ldexp(a2, dB); a3 = ldexp(a3, dB);                          \
          a4 = ldexp(a4, dB); a5 = ldexp(a5, dB);                          \
          a6 = ldexp(a6, dB); a7 = ldexp(a7, dB);                          \
        }                                                                  \
        double LB = ldexp(lB, slB - NB);                                   \
        double GB = ldexp(dB2, sdB - NB);                                  \
        const double WB0 = (double)SB0.x, WB1 = (double)SB0.y;             \
        const double WB2 = (double)SB0.z, WB3 = (double)SB0.w;             \
        const double WB4 = (double)SB1.x, WB5 = (double)SB1.y;             \
        const double WB6 = (double)SB1.z, WB7 = (double)SB1.w;             \
        double qb0 = WB0 * ((LB + GB) + a0);                               \
        double qb1 = WB1 * (a1 + a0);                                      \
        double qb2 = WB2 * (a2 + a1);                                      \
        double qb3 = WB3 * (a3 + a2);                                      \
        double qb4 = WB4 * (a4 + a3);                                      \
        double qb5 = WB5 * (a5 + a4);                                      \
        double qb6 = WB6 * (a6 + a5);                                      \
        double qb7 = WB7 * (a7 + a6);                                      \
        e0 = qb0;                                                          \
        e1 = fma(WB1, e0, qb1);                                            \
        e2 = fma(WB2, e1, qb2);                                            \
        e3 = fma(WB3, e2, qb3);                                            \
        e4 = fma(WB4, e3, qb4);                                            \
        e5 = fma(WB5, e4, qb5);                                            \
        e6 = fma(WB6, e5, qb6);                                            \
        e7 = fma(WB7, e6, qb7);                                            \
        e7A = a7;  /* already aligned to NB */                             \
        S = NB;                                                            \
      } else {                                                             \
        e0 = a0; e1 = a1; e2 = a2; e3 = a3;                                \
        e4 = a4; e5 = a5; e6 = a6; e7 = a7;                                \
        e7A = a7;                                                          \
        S = NA;                                                            \
      }                                                                    \
    }                                                                      \
    pvB = nvB; psB = ns;                                                   \
  }

  const int nsup = (M + 6) / 6 * 6;  // covers m = 0..M
  for (int mb = 0; mb < nsup; mb += 6) {
    SUP(mb + 0, K0a, K0b, K1a, K1b, K6a, K6b, K7a, K7b);
    SUP(mb + 1, K2a, K2b, K3a, K3b, K8a, K8b, K9a, K9b);
    SUP(mb + 2, K4a, K4b, K5a, K5b, K10a, K10b, K11a, K11b);
    SUP(mb + 3, K6a, K6b, K7a, K7b, K0a, K0b, K1a, K1b);
    SUP(mb + 4, K8a, K8b, K9a, K9b, K2a, K2b, K3a, K3b);
    SUP(mb + 5, K10a, K10b, K11a, K11b, K4a, K4b, K5a, K5b);
  }

  // drain all outstanding loads before the store (vmcnt counts stores too)
  asm volatile("s_waitcnt vmcnt(0)" ::: "memory");

  if (l == lt) {
    double out_v = (ct == 0) ? e0 : (ct == 1) ? e1 : (ct == 2) ? e2
                 : (ct == 3) ? e3 : (ct == 4) ? e4 : (ct == 5) ? e5
                 : (ct == 6) ? e6 : e7;
    double vv = (out_v > 0.) ? out_v : 1e-300;  // belt-and-braces
    double r = -C2D * (log2(vv) + (double)S);
    dist[p] = (float)(r * (double)invl);
  }
}

// ---------------------------------------------------------------------------
// Kernel 3: finalize — triplet loss + variance + MMD mean -> out[0]
// ---------------------------------------------------------------------------
__global__ __launch_bounds__(64) void finalize_kernel(
    const float* __restrict__ dist, const float* __restrict__ mmdpart,
    float* __restrict__ out) {
  int lane = threadIdx.x;
  float lv_po = 0.f;
  float dg[5];
#pragma unroll
  for (int g = 0; g < 5; ++g) dg[g] = 0.f;
  if (lane < 8) {
    const float* dr = dist + lane * 15;
    float dn[10];
#pragma unroll
    for (int g = 0; g < 5; ++g) dg[g] = dr[g];
#pragma unroll
    for (int k = 0; k < 10; ++k) dn[k] = dr[5 + k];
    float s1 = 0.f, s2 = 0.f;
    int nz = 0;
#pragma unroll
    for (int g = 0; g < 5; ++g) {
#pragma unroll
      for (int k = 0; k < 5; ++k) {
        float v2 = dg[g] + 1.0f - dn[k];
        if (v2 > 0.f) { s1 += v2; ++nz; }
      }
#pragma unroll
      for (int k = 5; k < 10; ++k) {
        float v2 = dg[g] + 1.0f - dn[k];
        if (v2 > 0.f) { s2 += v2; ++nz; }
      }
    }
    float only_pos = (dg[0] + dg[1] + dg[2] + dg[3] + dg[4]) * 0.002f;
    float lv = (s1 * 0.7f + s2 * 0.3f) / (float)(nz + 1);
    lv_po = lv + only_pos;
  }
  float tl = wred_sum(lv_po);
  tl = __shfl(tl, 0);

  // two-pass ddof=1 variance over the 40 dg values
  float psum = dg[0] + dg[1] + dg[2] + dg[3] + dg[4];
  float tsum = wred_sum(psum);
  float mean = __shfl(tsum, 0) * (1.f / 40.f);
  float pdev = 0.f;
  if (lane < 8) {
#pragma unroll
    for (int g = 0; g < 5; ++g) {
      float dd = dg[g] - mean;
      pdev = fmaf(dd, dd, pdev);
    }
  }
  float tdev = wred_sum(pdev);
  tdev = __shfl(tdev, 0);

  float msum = 0.f;
  for (int k2 = lane; k2 < 121; k2 += 64) msum += mmdpart[k2];
  float mt = wred_sum(msum);

  if (lane == 0) {
    float total_loss = tl * (1.f / 8.f);
    float var_g = (tdev / 39.f) * 0.1f;
    float mmd = mt * (1.f / 7744.f);
    out[0] = total_loss + mmd + var_g;
  }
}

__global__ __launch_bounds__(64) void zero_out_kernel(float* __restrict__ out,
                                                      int n) {
  int i = blockIdx.x * 64 + threadIdx.x;
  if (i < n) out[i] = 0.f;
}

// ---------------------------------------------------------------------------
extern "C" void kernel_launch(void* const* d_in, const int* in_sizes, int n_in,
                              void* d_out, int out_size, void* d_ws,
                              size_t ws_size, hipStream_t stream) {
  const float* data = (const float*)d_in[0];
  const int* lens = (const int*)d_in[1];
  float* out = (float*)d_out;
  char* ws = (char*)d_ws;

  const size_t HDR = 131072;  // dist/bwpart/mmdpart/l2buf region
  const size_t per_pair = (size_t)NSK * T_ * sizeof(float);  // 1.31 MB

  // Strict workspace guard: never touch bytes beyond ws_size.
  if (ws_size < HDR + per_pair) {
    zero_out_kernel<<<dim3((out_size + 63) / 64), 64, 0, stream>>>(out,
                                                                   out_size);
    return;
  }

  float* dist = (float*)(ws + 0);        // 120 floats
  float* bwpart = (float*)(ws + 1024);   // 253 floats
  float* mmdpart = (float*)(ws + 3072);  // 121 floats
  float* l2buf = (float*)(ws + 4096);    // 22*22*64 floats = 123904 B
  float* wbuf = (float*)(ws + HDR);

  size_t avail = ws_size - HDR;
  int PC = (int)(avail / per_pair);
  if (PC > NPAIR) PC = NPAIR;

  for (int p0 = 0; p0 < NPAIR; p0 += PC) {
    int pc = (NPAIR - p0) < PC ? (NPAIR - p0) : PC;
    int first = (p0 == 0) ? 1 : 0;
    gemm_mmd_kernel<<<dim3(64, pc + first), 256, 0, stream>>>(
        data, wbuf, p0, pc, l2buf, bwpart);
    dtw_mmdk_kernel<<<dim3(pc + (first ? 121 : 0)), 64, 0, stream>>>(
        wbuf, lens, dist, p0, pc, l2buf, bwpart, mmdpart);
  }
  finalize_kernel<<<dim3(1), 64, 0, stream>>>(dist, mmdpart, out);
}

// Round 18
// 181.338 us; speedup vs baseline: 1.5058x; 1.1483x over previous
//
#include <hip/hip_runtime.h>
#include <hip/hip_bf16.h>
#include <cstdint>
#include <cstddef>

#define T_ 512
#define DF 64
#define NPAIR 120
#define STEPW 16
#define NEGS (-(1 << 26))
#define NSK 640   // skewed-W rows per pair (638 used, padded)

// softmin constants
#define C1_ 0.28853900817779268f   // log2(e)/5
#define C2D 3.4657359027997265     // 5*ln(2), double

typedef unsigned short ushort_t;
using f32x4 = __attribute__((ext_vector_type(4))) float;
using bf16x8 = __attribute__((ext_vector_type(8))) short;

__device__ __forceinline__ float wred_sum(float v) {
#pragma unroll
  for (int o = 32; o > 0; o >>= 1) v += __shfl_down(v, o);
  return v;  // lane 0 holds the total
}

__device__ __forceinline__ int dexp(double x) {
  return (int)((__double_as_longlong(x) >> 52) & 0x7ff) - 1023;
}

__device__ __forceinline__ ushort_t f2bf(float x) {
  __hip_bfloat16 h = __float2bfloat16(x);
  return *reinterpret_cast<ushort_t*>(&h);
}
__device__ __forceinline__ float bf2f(ushort_t u) {
  __hip_bfloat16 h = *reinterpret_cast<__hip_bfloat16*>(&u);
  return __bfloat162float(h);
}

// unsinkable 16B global load to a named VGPR quad (HK pattern)
#define GLOAD(DST, PTR)                                                    \
  asm volatile("global_load_dwordx4 %0, %1, off"                           \
               : "=&v"(DST) : "v"(PTR) : "memory")

// ---------------------------------------------------------------------------
// Kernel 1 (FUSED): MFMA bf16-split gemm (blockIdx.y < npc) + mmd_l2
// (blockIdx.y == npc). D = ||x||^2 + ||y||^2 - 2*X.Y^T via
// mfma_f32_16x16x32_bf16: hi*hi + hi*lo + lo*hi (lo*lo ~2^-18, dropped).
// A/B fragments use the SAME (laneblock,elem)->k map, so any HW k-perm
// cancels; row/col maps follow the verified C/D layout. W stored in the
// skewed+permuted layout dtw consumes (r13-verified mapping).
// ---------------------------------------------------------------------------
__global__ __launch_bounds__(256) void gemm_mmd_kernel(
    const float* __restrict__ data, float* __restrict__ wbuf, int pair0,
    int npc, float* __restrict__ l2buf, float* __restrict__ bwpart) {
  __shared__ ushort_t XH[4096], XL[4096], YH[4096], YL[4096];  // 64x64 bf16
  __shared__ float nrmx[64];
  __shared__ float nrmy[64];

  if ((int)blockIdx.y == npc) {
    // ---- mmd_l2 path: wave g handles tri-pair b = blockIdx.x*4 + g
    const int tid = threadIdx.x;
    const int g = tid >> 6;
    const int f = tid & 63;
    const int b = (int)blockIdx.x * 4 + g;
    if (b < 253) {
      int u = 0, rem = b;
      while (rem >= 22 - u) { rem -= 22 - u; ++u; }
      int v = u + rem;
      float s = 0.f;
      if (u != v) {
        int iu = u < 11 ? u : u + 5;
        int iv = v < 11 ? v : v + 5;
        const float* A = data + (size_t)iu * (T_ * DF) + f;
        const float* B = data + (size_t)iv * (T_ * DF) + f;
#pragma unroll 8
        for (int t = 0; t < T_; ++t) {
          float dd = A[(size_t)t * DF] - B[(size_t)t * DF];
          s = fmaf(dd, dd, s);
        }
      }
      l2buf[(size_t)(u * 22 + v) * 64 + f] = s;
      l2buf[(size_t)(v * 22 + u) * 64 + f] = s;
      float tot = wred_sum(s);
      if (f == 0) bwpart[b] = 2.f * tot;
    }
    return;
  }

  const int tile = blockIdx.x;   // 0..63 = (bi<<3)|bj
  const int pc = blockIdx.y;
  const int p = pair0 + pc;
  const int w = p / 15;
  const int o = p - w * 15;
  const int aidx = w * STEPW;
  const int oidx = aidx + 1 + o;
  const int i0 = (tile >> 3) << 6;
  const int j0 = (tile & 7) << 6;
  const int tid = threadIdx.x;

  const float* Xg = data + (size_t)aidx * (T_ * DF);
  const float* Yg = data + (size_t)oidx * (T_ * DF);

  // stage + convert to split bf16, XOR-swizzled:
  // value (r, k) -> ushort addr r*64 + ((k>>3)^(r&7))*8 + (k&7)
#pragma unroll
  for (int l = 0; l < 4; ++l) {
    int idx = tid + l * 256;  // 0..1023
    int r = idx >> 4;
    int c = idx & 15;            // float4 col index: cols 4c..4c+3
    int g = c >> 1, h = c & 1;   // k-group, half
    int base = r * 64 + ((g ^ (r & 7)) << 3) + (h << 2);
    float4 xv = reinterpret_cast<const float4*>(Xg + (size_t)(i0 + r) * DF)[c];
    float4 yv = reinterpret_cast<const float4*>(Yg + (size_t)(j0 + r) * DF)[c];
    const float xa[4] = {xv.x, xv.y, xv.z, xv.w};
    const float ya[4] = {yv.x, yv.y, yv.z, yv.w};
#pragma unroll
    for (int e = 0; e < 4; ++e) {
      ushort_t xh = f2bf(xa[e]);
      XH[base + e] = xh;
      XL[base + e] = f2bf(xa[e] - bf2f(xh));
      ushort_t yh = f2bf(ya[e]);
      YH[base + e] = yh;
      YL[base + e] = f2bf(ya[e] - bf2f(yh));
    }
  }
  __syncthreads();

  // norms from staged hi+lo (deterministic, fixed order)
  if (tid < 128) {
    int r = tid & 63;
    float s = 0.f;
    if (tid < 64) {
#pragma unroll
      for (int k = 0; k < 64; ++k) {
        int a = r * 64 + (((k >> 3) ^ (r & 7)) << 3) + (k & 7);
        float x = bf2f(XH[a]) + bf2f(XL[a]);
        s = fmaf(x, x, s);
      }
      nrmx[r] = s;
    } else {
#pragma unroll
      for (int k = 0; k < 64; ++k) {
        int a = r * 64 + (((k >> 3) ^ (r & 7)) << 3) + (k & 7);
        float y = bf2f(YH[a]) + bf2f(YL[a]);
        s = fmaf(y, y, s);
      }
      nrmy[r] = s;
    }
  }
  __syncthreads();

  // MFMA phase: wave wid owns row-block 16*wid; loops col-blocks t=0..3
  const int lane = tid & 63;
  const int wid = tid >> 6;
  const int rowA = 16 * wid + (lane & 15);
  const int b16 = lane >> 4;  // k-block 0..3

  // A fragments (k-halves 0: groups b16, 1: groups 4+b16)
  const int aA0 = rowA * 64 + (((b16) ^ (rowA & 7)) << 3);
  const int aA1 = rowA * 64 + (((4 + b16) ^ (rowA & 7)) << 3);
  bf16x8 ah0 = *reinterpret_cast<const bf16x8*>(&XH[aA0]);
  bf16x8 ah1 = *reinterpret_cast<const bf16x8*>(&XH[aA1]);
  bf16x8 al0 = *reinterpret_cast<const bf16x8*>(&XL[aA0]);
  bf16x8 al1 = *reinterpret_cast<const bf16x8*>(&XL[aA1]);

  float* WpBase = wbuf + (size_t)pc * (NSK * T_);
  const float nx[4] = {nrmx[16 * wid + 0 + 4 * b16], 0.f, 0.f, 0.f};
  (void)nx;

#pragma unroll
  for (int t = 0; t < 4; ++t) {
    const int rowB = 16 * t + (lane & 15);
    const int aB0 = rowB * 64 + (((b16) ^ (rowB & 7)) << 3);
    const int aB1 = rowB * 64 + (((4 + b16) ^ (rowB & 7)) << 3);
    bf16x8 bh0 = *reinterpret_cast<const bf16x8*>(&YH[aB0]);
    bf16x8 bh1 = *reinterpret_cast<const bf16x8*>(&YH[aB1]);
    bf16x8 bl0 = *reinterpret_cast<const bf16x8*>(&YL[aB0]);
    bf16x8 bl1 = *reinterpret_cast<const bf16x8*>(&YL[aB1]);

    f32x4 acc = {0.f, 0.f, 0.f, 0.f};
    acc = __builtin_amdgcn_mfma_f32_16x16x32_bf16(ah0, bh0, acc, 0, 0, 0);
    acc = __builtin_amdgcn_mfma_f32_16x16x32_bf16(ah1, bh1, acc, 0, 0, 0);
    acc = __builtin_amdgcn_mfma_f32_16x16x32_bf16(ah0, bl0, acc, 0, 0, 0);
    acc = __builtin_amdgcn_mfma_f32_16x16x32_bf16(ah1, bl1, acc, 0, 0, 0);
    acc = __builtin_amdgcn_mfma_f32_16x16x32_bf16(al0, bh0, acc, 0, 0, 0);
    acc = __builtin_amdgcn_mfma_f32_16x16x32_bf16(al1, bh1, acc, 0, 0, 0);

    // epilogue: element (i,j); C/D layout col=lane&15, row=4*(lane>>4)+reg
    const int jg = j0 + 16 * t + (lane & 15);
    const float ny = nrmy[16 * t + (lane & 15)];
    const int g8 = jg >> 3;
    const int off = (((jg >> 2) & 1) << 8) + 4 * g8 + (jg & 3);
#pragma unroll
    for (int r = 0; r < 4; ++r) {
      const int ig = i0 + 16 * wid + 4 * b16 + r;
      float d = nrmx[16 * wid + 4 * b16 + r] + ny - 2.f * acc[r];
      float wv = __builtin_exp2f(-d * C1_);
      WpBase[(size_t)(ig + 2 * g8) * T_ + off] = wv;
    }
  }
}

// ---------------------------------------------------------------------------
// Kernel 2 (FUSED): dtw (blockIdx.x < npc) + mmd_k (blockIdx.x >= npc).
// dtw byte-identical to r15/r16/r17 (register-staged W, vmcnt(12)).
// ---------------------------------------------------------------------------
__global__ __launch_bounds__(64) void dtw_mmdk_kernel(
    const float* __restrict__ Wm, const int* __restrict__ lens,
    float* __restrict__ dist, int pair0, int npc,
    const float* __restrict__ l2buf, const float* __restrict__ bwpart,
    float* __restrict__ mmdpart) {
  if ((int)blockIdx.x >= npc) {
    int b = (int)blockIdx.x - npc;  // 0..120
    if (b < 121) {
      int a = b / 11, c = b - a * 11;
      int f = threadIdx.x;
      float bs = 0.f;
      for (int k2 = f; k2 < 253; k2 += 64) bs += bwpart[k2];
      bs = wred_sum(bs);
      float bw = __shfl(bs, 0) * (1.f / (462.f * 4.f));
      float xx = l2buf[(size_t)(a * 22 + c) * 64 + f];
      float yy = l2buf[(size_t)((11 + a) * 22 + (11 + c)) * 64 + f];
      float xy = l2buf[(size_t)(a * 22 + (11 + c)) * 64 + f];
      float yx = l2buf[(size_t)((11 + a) * 22 + c) * 64 + f];
      float term = 0.f;
      float ib = 1.f / bw;
#pragma unroll
      for (int i = 0; i < 5; ++i) {
        term += expf(-xx * ib) + expf(-yy * ib) - expf(-xy * ib)
              - expf(-yx * ib);
        ib *= 0.5f;
      }
      float tt = wred_sum(term);
      if (f == 0) mmdpart[b] = tt;
    }
    return;
  }

  const int pc = blockIdx.x;
  const int p = pair0 + pc;
  const int w = p / 15;
  const int o = p - w * 15;
  const int lx = lens[w * STEPW];
  const int ly = lens[w * STEPW + 1 + o];
  const int l = threadIdx.x;
  const int imax = lx - 1;
  const int jt = ly - 1;
  const int lt = jt >> 3, ct = jt & 7;
  const int M = lt + (imax >> 1);
  const float invl = 1.f / (float)(lx + ly);

  const float* wp = Wm + (size_t)pc * (NSK * T_) + 4 * l;

  float4 K0a, K0b, K1a, K1b, K2a, K2b, K3a, K3b;
  float4 K4a, K4b, K5a, K5b, K6a, K6b, K7a, K7b;
  float4 K8a, K8b, K9a, K9b, K10a, K10b, K11a, K11b;

#define LDROW(A, B, R)                                     \
  {                                                        \
    int r_ = (R); r_ = r_ > 637 ? 637 : r_;                \
    const float* p_ = wp + (size_t)r_ * T_;                \
    GLOAD(A, p_); GLOAD(B, p_ + 256);                      \
  }

  LDROW(K0a, K0b, 0); LDROW(K1a, K1b, 1);
  LDROW(K2a, K2b, 2); LDROW(K3a, K3b, 3);
  LDROW(K4a, K4b, 4); LDROW(K5a, K5b, 5);

  double e0 = 0., e1 = 0., e2 = 0., e3 = 0.;
  double e4 = 0., e5 = 0., e6 = 0., e7 = 0.;
  double e7A = 0.;
  int S = NEGS;
  double pvB = 0.;  int psB = NEGS;

#define SUP(MM, SA0, SA1, SB0, SB1, RA0, RA1, RB0, RB1)                    \
  {                                                                        \
    const int m_ = (MM);                                                   \
    double nvA = __shfl_up(e7A, 1);                                        \
    double nvB = __shfl_up(e7, 1);                                         \
    int ns = __shfl_up(S, 1);                                              \
    LDROW(RA0, RA1, 2 * m_ + 6);                                           \
    LDROW(RB0, RB1, 2 * m_ + 7);                                           \
    asm volatile("s_waitcnt vmcnt(12)" ::: "memory");                      \
    __builtin_amdgcn_sched_barrier(0);                                     \
    const int i = 2 * (m_ - l);                                            \
    double lA = nvA, dA = pvB, lB = nvB, dB2 = nvA;                        \
    int slA = ns, sdA = psB, slB = ns, sdB = ns;                           \
    if (l == 0) {                                                          \
      lA = 0.; slA = NEGS;                                                 \
      dA = (i == 0) ? 1. : 0.; sdA = (i == 0) ? 0 : NEGS;                  \
      lB = 0.; slB = NEGS;                                                 \
      dB2 = 0.; sdB = NEGS;                                                \
    }                                                                      \
    if ((unsigned)i <= (unsigned)imax) {                                   \
      double sum = ((e0 + e1) + (e2 + e3)) + ((e4 + e5) + (e6 + e7));      \
      int NA = max(S + dexp(sum), max(slA + dexp(lA), sdA + dexp(dA)));    \
      const int dS = S - NA;                                               \
      if (dS != 0) {                                                       \
        e0 = ldexp(e0, dS); e1 = ldexp(e1, dS);                            \
        e2 = ldexp(e2, dS); e3 = ldexp(e3, dS);                            \
        e4 = ldexp(e4, dS); e5 = ldexp(e5, dS);                            \
        e6 = ldexp(e6, dS); e7 = ldexp(e7, dS);                            \
      }                                                                    \
      double L = ldexp(lA, slA - NA);                                      \
      double G = ldexp(dA, sdA - NA);                                      \
      const double WA0 = (double)SA0.x, WA1 = (double)SA0.y;               \
      const double WA2 = (double)SA0.z, WA3 = (double)SA0.w;               \
      const double WA4 = (double)SA1.x, WA5 = (double)SA1.y;               \
      const double WA6 = (double)SA1.z, WA7 = (double)SA1.w;               \
      double qa0 = WA0 * ((L + G) + e0);                                   \
      double qa1 = WA1 * (e1 + e0);                                        \
      double qa2 = WA2 * (e2 + e1);                                        \
      double qa3 = WA3 * (e3 + e2);                                        \
      double qa4 = WA4 * (e4 + e3);                                        \
      double qa5 = WA5 * (e5 + e4);                                        \
      double qa6 = WA6 * (e6 + e5);                                        \
      double qa7 = WA7 * (e7 + e6);                                        \
      double a0 = qa0;                                                     \
      double a1 = fma(WA1, a0, qa1);                                       \
      double a2 = fma(WA2, a1, qa2);                                       \
      double a3 = fma(WA3, a2, qa3);                                       \
      double a4 = fma(WA4, a3, qa4);                                       \
      double a5 = fma(WA5, a4, qa5);                                       \
      double a6 = fma(WA6, a5, qa6);                                       \
      double a7 = fma(WA7, a6, qa7);                                       \
      if (i + 1 <= imax) {                                                 \
        int NB = max(NA, max(slB + dexp(lB), sdB + dexp(dB2)));            \
        const int dB = NA - NB;                                            \
        if (dB != 0) {                                                     \
          a0 = ldexp(a0, dB); a1 = ldexp(a1, dB);                          \
          a2 = ldexp(a2, dB); a3 = ldexp(a3, dB);                          \
          a4 = ldexp(a4, dB); a5 = ldexp(a5, dB);                          \
          a6 = ldexp(a6, dB); a7 = ldexp(a7, dB);                          \
        }                                                                  \
        double LB = ldexp(lB, slB - NB);                                   \
        double GB = ldexp(dB2, sdB - NB);                                  \
        const double WB0 = (double)SB0.x, WB1 = (double)SB0.y;             \
        const double WB2 = (double)SB0.z, WB3 = (double)SB0.w;             \
        const double WB4 = (double)SB1.x, WB5 = (double)SB1.y;             \
        const double WB6 = (double)SB1.z, WB7 = (double)SB1.w;             \
        double qb0 = WB0 * ((LB + GB) + a0);                               \
        double qb1 = WB1 * (a1 + a0);                                      \
        double qb2 = WB2 * (a2 + a1);                                      \
        double qb3 = WB3 * (a3 + a2);                                      \
        double qb4 = WB4 * (a4 + a3);                                      \
        double qb5 = WB5 * (a5 + a4);                                      \
        double qb6 = WB6 * (a6 + a5);                                      \
        double qb7 = WB7 * (a7 + a6);                                      \
        e0 = qb0;                                                          \
        e1 = fma(WB1, e0, qb1);                                            \
        e2 = fma(WB2, e1, qb2);                                            \
        e3 = fma(WB3, e2, qb3);                                            \
        e4 = fma(WB4, e3, qb4);                                            \
        e5 = fma(WB5, e4, qb5);                                            \
        e6 = fma(WB6, e5, qb6);                                            \
        e7 = fma(WB7, e6, qb7);                                            \
        e7A = a7;                                                          \
        S = NB;                                                            \
      } else {                                                             \
        e0 = a0; e1 = a1; e2 = a2; e3 = a3;                                \
        e4 = a4; e5 = a5; e6 = a6; e7 = a7;                                \
        e7A = a7;                                                          \
        S = NA;                                                            \
      }                                                                    \
    }                                                                      \
    pvB = nvB; psB = ns;                                                   \
  }

  const int nsup = (M + 6) / 6 * 6;
  for (int mb = 0; mb < nsup; mb += 6) {
    SUP(mb + 0, K0a, K0b, K1a, K1b, K6a, K6b, K7a, K7b);
    SUP(mb + 1, K2a, K2b, K3a, K3b, K8a, K8b, K9a, K9b);
    SUP(mb + 2, K4a, K4b, K5a, K5b, K10a, K10b, K11a, K11b);
    SUP(mb + 3, K6a, K6b, K7a, K7b, K0a, K0b, K1a, K1b);
    SUP(mb + 4, K8a, K8b, K9a, K9b, K2a, K2b, K3a, K3b);
    SUP(mb + 5, K10a, K10b, K11a, K11b, K4a, K4b, K5a, K5b);
  }

  asm volatile("s_waitcnt vmcnt(0)" ::: "memory");

  if (l == lt) {
    double out_v = (ct == 0) ? e0 : (ct == 1) ? e1 : (ct == 2) ? e2
                 : (ct == 3) ? e3 : (ct == 4) ? e4 : (ct == 5) ? e5
                 : (ct == 6) ? e6 : e7;
    double vv = (out_v > 0.) ? out_v : 1e-300;
    double r = -C2D * (log2(vv) + (double)S);
    dist[p] = (float)(r * (double)invl);
  }
}

// ---------------------------------------------------------------------------
// Kernel 3: finalize — triplet loss + variance + MMD mean -> out[0]
// ---------------------------------------------------------------------------
__global__ __launch_bounds__(64) void finalize_kernel(
    const float* __restrict__ dist, const float* __restrict__ mmdpart,
    float* __restrict__ out) {
  int lane = threadIdx.x;
  float lv_po = 0.f;
  float dg[5];
#pragma unroll
  for (int g = 0; g < 5; ++g) dg[g] = 0.f;
  if (lane < 8) {
    const float* dr = dist + lane * 15;
    float dn[10];
#pragma unroll
    for (int g = 0; g < 5; ++g) dg[g] = dr[g];
#pragma unroll
    for (int k = 0; k < 10; ++k) dn[k] = dr[5 + k];
    float s1 = 0.f, s2 = 0.f;
    int nz = 0;
#pragma unroll
    for (int g = 0; g < 5; ++g) {
#pragma unroll
      for (int k = 0; k < 5; ++k) {
        float v2 = dg[g] + 1.0f - dn[k];
        if (v2 > 0.f) { s1 += v2; ++nz; }
      }
#pragma unroll
      for (int k = 5; k < 10; ++k) {
        float v2 = dg[g] + 1.0f - dn[k];
        if (v2 > 0.f) { s2 += v2; ++nz; }
      }
    }
    float only_pos = (dg[0] + dg[1] + dg[2] + dg[3] + dg[4]) * 0.002f;
    float lv = (s1 * 0.7f + s2 * 0.3f) / (float)(nz + 1);
    lv_po = lv + only_pos;
  }
  float tl = wred_sum(lv_po);
  tl = __shfl(tl, 0);

  float psum = dg[0] + dg[1] + dg[2] + dg[3] + dg[4];
  float tsum = wred_sum(psum);
  float mean = __shfl(tsum, 0) * (1.f / 40.f);
  float pdev = 0.f;
  if (lane < 8) {
#pragma unroll
    for (int g = 0; g < 5; ++g) {
      float dd = dg[g] - mean;
      pdev = fmaf(dd, dd, pdev);
    }
  }
  float tdev = wred_sum(pdev);
  tdev = __shfl(tdev, 0);

  float msum = 0.f;
  for (int k2 = lane; k2 < 121; k2 += 64) msum += mmdpart[k2];
  float mt = wred_sum(msum);

  if (lane == 0) {
    float total_loss = tl * (1.f / 8.f);
    float var_g = (tdev / 39.f) * 0.1f;
    float mmd = mt * (1.f / 7744.f);
    out[0] = total_loss + mmd + var_g;
  }
}

__global__ __launch_bounds__(64) void zero_out_kernel(float* __restrict__ out,
                                                      int n) {
  int i = blockIdx.x * 64 + threadIdx.x;
  if (i < n) out[i] = 0.f;
}

// ---------------------------------------------------------------------------
extern "C" void kernel_launch(void* const* d_in, const int* in_sizes, int n_in,
                              void* d_out, int out_size, void* d_ws,
                              size_t ws_size, hipStream_t stream) {
  const float* data = (const float*)d_in[0];
  const int* lens = (const int*)d_in[1];
  float* out = (float*)d_out;
  char* ws = (char*)d_ws;

  const size_t HDR = 131072;
  const size_t per_pair = (size_t)NSK * T_ * sizeof(float);  // 1.31 MB

  if (ws_size < HDR + per_pair) {
    zero_out_kernel<<<dim3((out_size + 63) / 64), 64, 0, stream>>>(out,
                                                                   out_size);
    return;
  }

  float* dist = (float*)(ws + 0);
  float* bwpart = (float*)(ws + 1024);
  float* mmdpart = (float*)(ws + 3072);
  float* l2buf = (float*)(ws + 4096);
  float* wbuf = (float*)(ws + HDR);

  size_t avail = ws_size - HDR;
  int PC = (int)(avail / per_pair);
  if (PC > NPAIR) PC = NPAIR;

  for (int p0 = 0; p0 < NPAIR; p0 += PC) {
    int pc = (NPAIR - p0) < PC ? (NPAIR - p0) : PC;
    int first = (p0 == 0) ? 1 : 0;
    gemm_mmd_kernel<<<dim3(64, pc + first), 256, 0, stream>>>(
        data, wbuf, p0, pc, l2buf, bwpart);
    dtw_mmdk_kernel<<<dim3(pc + (first ? 121 : 0)), 64, 0, stream>>>(
        wbuf, lens, dist, p0, pc, l2buf, bwpart, mmdpart);
  }
  finalize_kernel<<<dim3(1), 64, 0, stream>>>(dist, mmdpart, out);
}

// Round 19
// 180.084 us; speedup vs baseline: 1.5163x; 1.0070x over previous
//
#include <hip/hip_runtime.h>
#include <hip/hip_bf16.h>
#include <cstdint>
#include <cstddef>

#define T_ 512
#define DF 64
#define NPAIR 120
#define STEPW 16
#define NEGS (-(1 << 26))
#define NSK 640   // skewed-W rows per pair (638 used, padded)

// softmin constants
#define C1_ 0.28853900817779268f   // log2(e)/5
#define C2D 3.4657359027997265     // 5*ln(2), double

typedef unsigned short ushort_t;
using f32x4 = __attribute__((ext_vector_type(4))) float;
using bf16x8 = __attribute__((ext_vector_type(8))) short;

__device__ __forceinline__ float wred_sum(float v) {
#pragma unroll
  for (int o = 32; o > 0; o >>= 1) v += __shfl_down(v, o);
  return v;  // lane 0 holds the total
}

__device__ __forceinline__ int dexp(double x) {
  return (int)((__double_as_longlong(x) >> 52) & 0x7ff) - 1023;
}

__device__ __forceinline__ ushort_t f2bf(float x) {
  __hip_bfloat16 h = __float2bfloat16(x);
  return *reinterpret_cast<ushort_t*>(&h);
}
__device__ __forceinline__ float bf2f(ushort_t u) {
  __hip_bfloat16 h = *reinterpret_cast<__hip_bfloat16*>(&u);
  return __bfloat162float(h);
}

// unsinkable 16B global load to a named VGPR quad (HK pattern)
#define GLOAD(DST, PTR)                                                    \
  asm volatile("global_load_dwordx4 %0, %1, off"                           \
               : "=&v"(DST) : "v"(PTR) : "memory")

// ---------------------------------------------------------------------------
// Kernel 1 (FUSED): MFMA bf16-split gemm (blockIdx.y < npc) + mmd_l2
// (blockIdx.y == npc).  Byte-identical to r18 (verified absmax 0).
// ---------------------------------------------------------------------------
__global__ __launch_bounds__(256) void gemm_mmd_kernel(
    const float* __restrict__ data, float* __restrict__ wbuf, int pair0,
    int npc, float* __restrict__ l2buf, float* __restrict__ bwpart) {
  __shared__ ushort_t XH[4096], XL[4096], YH[4096], YL[4096];  // 64x64 bf16
  __shared__ float nrmx[64];
  __shared__ float nrmy[64];

  if ((int)blockIdx.y == npc) {
    const int tid = threadIdx.x;
    const int g = tid >> 6;
    const int f = tid & 63;
    const int b = (int)blockIdx.x * 4 + g;
    if (b < 253) {
      int u = 0, rem = b;
      while (rem >= 22 - u) { rem -= 22 - u; ++u; }
      int v = u + rem;
      float s = 0.f;
      if (u != v) {
        int iu = u < 11 ? u : u + 5;
        int iv = v < 11 ? v : v + 5;
        const float* A = data + (size_t)iu * (T_ * DF) + f;
        const float* B = data + (size_t)iv * (T_ * DF) + f;
#pragma unroll 8
        for (int t = 0; t < T_; ++t) {
          float dd = A[(size_t)t * DF] - B[(size_t)t * DF];
          s = fmaf(dd, dd, s);
        }
      }
      l2buf[(size_t)(u * 22 + v) * 64 + f] = s;
      l2buf[(size_t)(v * 22 + u) * 64 + f] = s;
      float tot = wred_sum(s);
      if (f == 0) bwpart[b] = 2.f * tot;
    }
    return;
  }

  const int tile = blockIdx.x;   // 0..63 = (bi<<3)|bj
  const int pc = blockIdx.y;
  const int p = pair0 + pc;
  const int w = p / 15;
  const int o = p - w * 15;
  const int aidx = w * STEPW;
  const int oidx = aidx + 1 + o;
  const int i0 = (tile >> 3) << 6;
  const int j0 = (tile & 7) << 6;
  const int tid = threadIdx.x;

  const float* Xg = data + (size_t)aidx * (T_ * DF);
  const float* Yg = data + (size_t)oidx * (T_ * DF);

#pragma unroll
  for (int l = 0; l < 4; ++l) {
    int idx = tid + l * 256;  // 0..1023
    int r = idx >> 4;
    int c = idx & 15;
    int g = c >> 1, h = c & 1;
    int base = r * 64 + ((g ^ (r & 7)) << 3) + (h << 2);
    float4 xv = reinterpret_cast<const float4*>(Xg + (size_t)(i0 + r) * DF)[c];
    float4 yv = reinterpret_cast<const float4*>(Yg + (size_t)(j0 + r) * DF)[c];
    const float xa[4] = {xv.x, xv.y, xv.z, xv.w};
    const float ya[4] = {yv.x, yv.y, yv.z, yv.w};
#pragma unroll
    for (int e = 0; e < 4; ++e) {
      ushort_t xh = f2bf(xa[e]);
      XH[base + e] = xh;
      XL[base + e] = f2bf(xa[e] - bf2f(xh));
      ushort_t yh = f2bf(ya[e]);
      YH[base + e] = yh;
      YL[base + e] = f2bf(ya[e] - bf2f(yh));
    }
  }
  __syncthreads();

  if (tid < 128) {
    int r = tid & 63;
    float s = 0.f;
    if (tid < 64) {
#pragma unroll
      for (int k = 0; k < 64; ++k) {
        int a = r * 64 + (((k >> 3) ^ (r & 7)) << 3) + (k & 7);
        float x = bf2f(XH[a]) + bf2f(XL[a]);
        s = fmaf(x, x, s);
      }
      nrmx[r] = s;
    } else {
#pragma unroll
      for (int k = 0; k < 64; ++k) {
        int a = r * 64 + (((k >> 3) ^ (r & 7)) << 3) + (k & 7);
        float y = bf2f(YH[a]) + bf2f(YL[a]);
        s = fmaf(y, y, s);
      }
      nrmy[r] = s;
    }
  }
  __syncthreads();

  const int lane = tid & 63;
  const int wid = tid >> 6;
  const int rowA = 16 * wid + (lane & 15);
  const int b16 = lane >> 4;

  const int aA0 = rowA * 64 + (((b16) ^ (rowA & 7)) << 3);
  const int aA1 = rowA * 64 + (((4 + b16) ^ (rowA & 7)) << 3);
  bf16x8 ah0 = *reinterpret_cast<const bf16x8*>(&XH[aA0]);
  bf16x8 ah1 = *reinterpret_cast<const bf16x8*>(&XH[aA1]);
  bf16x8 al0 = *reinterpret_cast<const bf16x8*>(&XL[aA0]);
  bf16x8 al1 = *reinterpret_cast<const bf16x8*>(&XL[aA1]);

  float* WpBase = wbuf + (size_t)pc * (NSK * T_);

#pragma unroll
  for (int t = 0; t < 4; ++t) {
    const int rowB = 16 * t + (lane & 15);
    const int aB0 = rowB * 64 + (((b16) ^ (rowB & 7)) << 3);
    const int aB1 = rowB * 64 + (((4 + b16) ^ (rowB & 7)) << 3);
    bf16x8 bh0 = *reinterpret_cast<const bf16x8*>(&YH[aB0]);
    bf16x8 bh1 = *reinterpret_cast<const bf16x8*>(&YH[aB1]);
    bf16x8 bl0 = *reinterpret_cast<const bf16x8*>(&YL[aB0]);
    bf16x8 bl1 = *reinterpret_cast<const bf16x8*>(&YL[aB1]);

    f32x4 acc = {0.f, 0.f, 0.f, 0.f};
    acc = __builtin_amdgcn_mfma_f32_16x16x32_bf16(ah0, bh0, acc, 0, 0, 0);
    acc = __builtin_amdgcn_mfma_f32_16x16x32_bf16(ah1, bh1, acc, 0, 0, 0);
    acc = __builtin_amdgcn_mfma_f32_16x16x32_bf16(ah0, bl0, acc, 0, 0, 0);
    acc = __builtin_amdgcn_mfma_f32_16x16x32_bf16(ah1, bl1, acc, 0, 0, 0);
    acc = __builtin_amdgcn_mfma_f32_16x16x32_bf16(al0, bh0, acc, 0, 0, 0);
    acc = __builtin_amdgcn_mfma_f32_16x16x32_bf16(al1, bh1, acc, 0, 0, 0);

    const int jg = j0 + 16 * t + (lane & 15);
    const float ny = nrmy[16 * t + (lane & 15)];
    const int g8 = jg >> 3;
    const int off = (((jg >> 2) & 1) << 8) + 4 * g8 + (jg & 3);
#pragma unroll
    for (int r = 0; r < 4; ++r) {
      const int ig = i0 + 16 * wid + 4 * b16 + r;
      float d = nrmx[16 * wid + 4 * b16 + r] + ny - 2.f * acc[r];
      float wv = __builtin_exp2f(-d * C1_);
      WpBase[(size_t)(ig + 2 * g8) * T_ + off] = wv;
    }
  }
}

// ---------------------------------------------------------------------------
// Kernel 2 (FUSED): dtw (blockIdx.x < npc) + mmd_k (blockIdx.x >= npc).
// r19: shuffles moved OFF the critical path while keeping the 2-row stagger:
//  - row-A boundary (lane l-1's a7 aligned to NB, + NB) arrives via an
//    END-of-previous-superstep shuffle of persistent sendA regs (written
//    unconditionally -> no divergence hazard; inactive lanes hold (0,NEGS));
//  - row-B left (lane l-1's e7) still shuffled at superstep start but now
//    consumed only AFTER row A (~300 cy slack);
//  - the separate scale shuffle is gone (nvB's scale == received NB).
// Critical path is now pure fp64 math: e7 -> sum -> NA -> chainA -> NB ->
// chainB.  Numerics identical to r15-r18.
// ---------------------------------------------------------------------------
__global__ __launch_bounds__(64) void dtw_mmdk_kernel(
    const float* __restrict__ Wm, const int* __restrict__ lens,
    float* __restrict__ dist, int pair0, int npc,
    const float* __restrict__ l2buf, const float* __restrict__ bwpart,
    float* __restrict__ mmdpart) {
  if ((int)blockIdx.x >= npc) {
    int b = (int)blockIdx.x - npc;  // 0..120
    if (b < 121) {
      int a = b / 11, c = b - a * 11;
      int f = threadIdx.x;
      float bs = 0.f;
      for (int k2 = f; k2 < 253; k2 += 64) bs += bwpart[k2];
      bs = wred_sum(bs);
      float bw = __shfl(bs, 0) * (1.f / (462.f * 4.f));
      float xx = l2buf[(size_t)(a * 22 + c) * 64 + f];
      float yy = l2buf[(size_t)((11 + a) * 22 + (11 + c)) * 64 + f];
      float xy = l2buf[(size_t)(a * 22 + (11 + c)) * 64 + f];
      float yx = l2buf[(size_t)((11 + a) * 22 + c) * 64 + f];
      float term = 0.f;
      float ib = 1.f / bw;
#pragma unroll
      for (int i = 0; i < 5; ++i) {
        term += expf(-xx * ib) + expf(-yy * ib) - expf(-xy * ib)
              - expf(-yx * ib);
        ib *= 0.5f;
      }
      float tt = wred_sum(term);
      if (f == 0) mmdpart[b] = tt;
    }
    return;
  }

  const int pc = blockIdx.x;
  const int p = pair0 + pc;
  const int w = p / 15;
  const int o = p - w * 15;
  const int lx = lens[w * STEPW];
  const int ly = lens[w * STEPW + 1 + o];
  const int l = threadIdx.x;
  const int imax = lx - 1;
  const int jt = ly - 1;
  const int lt = jt >> 3, ct = jt & 7;
  const int M = lt + (imax >> 1);
  const float invl = 1.f / (float)(lx + ly);

  const float* wp = Wm + (size_t)pc * (NSK * T_) + 4 * l;

  float4 K0a, K0b, K1a, K1b, K2a, K2b, K3a, K3b;
  float4 K4a, K4b, K5a, K5b, K6a, K6b, K7a, K7b;
  float4 K8a, K8b, K9a, K9b, K10a, K10b, K11a, K11b;

#define LDROW(A, B, R)                                     \
  {                                                        \
    int r_ = (R); r_ = r_ > 637 ? 637 : r_;                \
    const float* p_ = wp + (size_t)r_ * T_;                \
    GLOAD(A, p_); GLOAD(B, p_ + 256);                      \
  }

  LDROW(K0a, K0b, 0); LDROW(K1a, K1b, 1);
  LDROW(K2a, K2b, 2); LDROW(K3a, K3b, 3);
  LDROW(K4a, K4b, 4); LDROW(K5a, K5b, 5);

  // committed row-B E (fp64 mantissas, shared block exponent S)
  double e0 = 0., e1 = 0., e2 = 0., e3 = 0.;
  double e4 = 0., e5 = 0., e6 = 0., e7 = 0.;
  int S = NEGS;
  // persistent send regs (a7 aligned to NB, + NB); (0,NEGS) when inactive
  double sendA_v = 0.;  int sendA_s = NEGS;
  // received from lane l-1: its sendA of previous superstep
  double rAv = 0.;  int rAs = NEGS;
  // lane l-1's row-B e7 of superstep m-2 (+ its scale)
  double pvB = 0.;  int psB = NEGS;

#define SUP(MM, SA0, SA1, SB0, SB1, RA0, RA1, RB0, RB1)                    \
  {                                                                        \
    const int m_ = (MM);                                                   \
    double nvB = __shfl_up(e7, 1);  /* row-B left; scale == rAs */         \
    LDROW(RA0, RA1, 2 * m_ + 6);                                           \
    LDROW(RB0, RB1, 2 * m_ + 7);                                           \
    asm volatile("s_waitcnt vmcnt(12)" ::: "memory");                      \
    __builtin_amdgcn_sched_barrier(0);                                     \
    const int i = 2 * (m_ - l);                                            \
    double lA = rAv, dA = pvB, lB = nvB, dB2 = rAv;                        \
    int slA = rAs, sdA = psB, slB = rAs, sdB = rAs;                        \
    if (l == 0) {                                                          \
      lA = 0.; slA = NEGS;                                                 \
      dA = (i == 0) ? 1. : 0.; sdA = (i == 0) ? 0 : NEGS;                  \
      lB = 0.; slB = NEGS;                                                 \
      dB2 = 0.; sdB = NEGS;                                                \
    }                                                                      \
    if ((unsigned)i <= (unsigned)imax) {                                   \
      double sum = ((e0 + e1) + (e2 + e3)) + ((e4 + e5) + (e6 + e7));      \
      int NA = max(S + dexp(sum), max(slA + dexp(lA), sdA + dexp(dA)));    \
      const int dS = S - NA;                                               \
      if (dS != 0) {                                                       \
        e0 = ldexp(e0, dS); e1 = ldexp(e1, dS);                            \
        e2 = ldexp(e2, dS); e3 = ldexp(e3, dS);                            \
        e4 = ldexp(e4, dS); e5 = ldexp(e5, dS);                            \
        e6 = ldexp(e6, dS); e7 = ldexp(e7, dS);                            \
      }                                                                    \
      double L = ldexp(lA, slA - NA);                                      \
      double G = ldexp(dA, sdA - NA);                                      \
      const double WA0 = (double)SA0.x, WA1 = (double)SA0.y;               \
      const double WA2 = (double)SA0.z, WA3 = (double)SA0.w;               \
      const double WA4 = (double)SA1.x, WA5 = (double)SA1.y;               \
      const double WA6 = (double)SA1.z, WA7 = (double)SA1.w;               \
      double qa0 = WA0 * ((L + G) + e0);                                   \
      double qa1 = WA1 * (e1 + e0);                                        \
      double qa2 = WA2 * (e2 + e1);                                        \
      double qa3 = WA3 * (e3 + e2);                                        \
      double qa4 = WA4 * (e4 + e3);                                        \
      double qa5 = WA5 * (e5 + e4);                                        \
      double qa6 = WA6 * (e6 + e5);                                        \
      double qa7 = WA7 * (e7 + e6);                                        \
      double a0 = qa0;                                                     \
      double a1 = fma(WA1, a0, qa1);                                       \
      double a2 = fma(WA2, a1, qa2);                                       \
      double a3 = fma(WA3, a2, qa3);                                       \
      double a4 = fma(WA4, a3, qa4);                                       \
      double a5 = fma(WA5, a4, qa5);                                       \
      double a6 = fma(WA6, a5, qa6);                                       \
      double a7 = fma(WA7, a6, qa7);                                       \
      if (i + 1 <= imax) {                                                 \
        int NB = max(NA, max(slB + dexp(lB), sdB + dexp(dB2)));            \
        const int dB = NA - NB;                                            \
        if (dB != 0) {                                                     \
          a0 = ldexp(a0, dB); a1 = ldexp(a1, dB);                          \
          a2 = ldexp(a2, dB); a3 = ldexp(a3, dB);                          \
          a4 = ldexp(a4, dB); a5 = ldexp(a5, dB);                          \
          a6 = ldexp(a6, dB); a7 = ldexp(a7, dB);                          \
        }                                                                  \
        sendA_v = a7; sendA_s = NB;                                        \
        double LB = ldexp(lB, slB - NB);                                   \
        double GB = ldexp(dB2, sdB - NB);                                  \
        const double WB0 = (double)SB0.x, WB1 = (double)SB0.y;             \
        const double WB2 = (double)SB0.z, WB3 = (double)SB0.w;             \
        const double WB4 = (double)SB1.x, WB5 = (double)SB1.y;             \
        const double WB6 = (double)SB1.z, WB7 = (double)SB1.w;             \
        double qb0 = WB0 * ((LB + GB) + a0);                               \
        double qb1 = WB1 * (a1 + a0);                                      \
        double qb2 = WB2 * (a2 + a1);                                      \
        double qb3 = WB3 * (a3 + a2);                                      \
        double qb4 = WB4 * (a4 + a3);                                      \
        double qb5 = WB5 * (a5 + a4);                                      \
        double qb6 = WB6 * (a6 + a5);                                      \
        double qb7 = WB7 * (a7 + a6);                                      \
        e0 = qb0;                                                          \
        e1 = fma(WB1, e0, qb1);                                            \
        e2 = fma(WB2, e1, qb2);                                            \
        e3 = fma(WB3, e2, qb3);                                            \
        e4 = fma(WB4, e3, qb4);                                            \
        e5 = fma(WB5, e4, qb5);                                            \
        e6 = fma(WB6, e5, qb6);                                            \
        e7 = fma(WB7, e6, qb7);                                            \
        S = NB;                                                            \
      } else {                                                             \
        e0 = a0; e1 = a1; e2 = a2; e3 = a3;                                \
        e4 = a4; e5 = a5; e6 = a6; e7 = a7;                                \
        sendA_v = a7; sendA_s = NA;                                        \
        S = NA;                                                            \
      }                                                                    \
    }                                                                      \
    pvB = nvB; psB = rAs;                                                  \
    rAv = __shfl_up(sendA_v, 1);                                           \
    rAs = __shfl_up(sendA_s, 1);                                           \
  }

  const int nsup = (M + 6) / 6 * 6;
  for (int mb = 0; mb < nsup; mb += 6) {
    SUP(mb + 0, K0a, K0b, K1a, K1b, K6a, K6b, K7a, K7b);
    SUP(mb + 1, K2a, K2b, K3a, K3b, K8a, K8b, K9a, K9b);
    SUP(mb + 2, K4a, K4b, K5a, K5b, K10a, K10b, K11a, K11b);
    SUP(mb + 3, K6a, K6b, K7a, K7b, K0a, K0b, K1a, K1b);
    SUP(mb + 4, K8a, K8b, K9a, K9b, K2a, K2b, K3a, K3b);
    SUP(mb + 5, K10a, K10b, K11a, K11b, K4a, K4b, K5a, K5b);
  }

  asm volatile("s_waitcnt vmcnt(0)" ::: "memory");

  if (l == lt) {
    double out_v = (ct == 0) ? e0 : (ct == 1) ? e1 : (ct == 2) ? e2
                 : (ct == 3) ? e3 : (ct == 4) ? e4 : (ct == 5) ? e5
                 : (ct == 6) ? e6 : e7;
    double vv = (out_v > 0.) ? out_v : 1e-300;
    double r = -C2D * (log2(vv) + (double)S);
    dist[p] = (float)(r * (double)invl);
  }
}

// ---------------------------------------------------------------------------
// Kernel 3: finalize — triplet loss + variance + MMD mean -> out[0]
// ---------------------------------------------------------------------------
__global__ __launch_bounds__(64) void finalize_kernel(
    const float* __restrict__ dist, const float* __restrict__ mmdpart,
    float* __restrict__ out) {
  int lane = threadIdx.x;
  float lv_po = 0.f;
  float dg[5];
#pragma unroll
  for (int g = 0; g < 5; ++g) dg[g] = 0.f;
  if (lane < 8) {
    const float* dr = dist + lane * 15;
    float dn[10];
#pragma unroll
    for (int g = 0; g < 5; ++g) dg[g] = dr[g];
#pragma unroll
    for (int k = 0; k < 10; ++k) dn[k] = dr[5 + k];
    float s1 = 0.f, s2 = 0.f;
    int nz = 0;
#pragma unroll
    for (int g = 0; g < 5; ++g) {
#pragma unroll
      for (int k = 0; k < 5; ++k) {
        float v2 = dg[g] + 1.0f - dn[k];
        if (v2 > 0.f) { s1 += v2; ++nz; }
      }
#pragma unroll
      for (int k = 5; k < 10; ++k) {
        float v2 = dg[g] + 1.0f - dn[k];
        if (v2 > 0.f) { s2 += v2; ++nz; }
      }
    }
    float only_pos = (dg[0] + dg[1] + dg[2] + dg[3] + dg[4]) * 0.002f;
    float lv = (s1 * 0.7f + s2 * 0.3f) / (float)(nz + 1);
    lv_po = lv + only_pos;
  }
  float tl = wred_sum(lv_po);
  tl = __shfl(tl, 0);

  float psum = dg[0] + dg[1] + dg[2] + dg[3] + dg[4];
  float tsum = wred_sum(psum);
  float mean = __shfl(tsum, 0) * (1.f / 40.f);
  float pdev = 0.f;
  if (lane < 8) {
#pragma unroll
    for (int g = 0; g < 5; ++g) {
      float dd = dg[g] - mean;
      pdev = fmaf(dd, dd, pdev);
    }
  }
  float tdev = wred_sum(pdev);
  tdev = __shfl(tdev, 0);

  float msum = 0.f;
  for (int k2 = lane; k2 < 121; k2 += 64) msum += mmdpart[k2];
  float mt = wred_sum(msum);

  if (lane == 0) {
    float total_loss = tl * (1.f / 8.f);
    float var_g = (tdev / 39.f) * 0.1f;
    float mmd = mt * (1.f / 7744.f);
    out[0] = total_loss + mmd + var_g;
  }
}

__global__ __launch_bounds__(64) void zero_out_kernel(float* __restrict__ out,
                                                      int n) {
  int i = blockIdx.x * 64 + threadIdx.x;
  if (i < n) out[i] = 0.f;
}

// ---------------------------------------------------------------------------
extern "C" void kernel_launch(void* const* d_in, const int* in_sizes, int n_in,
                              void* d_out, int out_size, void* d_ws,
                              size_t ws_size, hipStream_t stream) {
  const float* data = (const float*)d_in[0];
  const int* lens = (const int*)d_in[1];
  float* out = (float*)d_out;
  char* ws = (char*)d_ws;

  const size_t HDR = 131072;
  const size_t per_pair = (size_t)NSK * T_ * sizeof(float);  // 1.31 MB

  if (ws_size < HDR + per_pair) {
    zero_out_kernel<<<dim3((out_size + 63) / 64), 64, 0, stream>>>(out,
                                                                   out_size);
    return;
  }

  float* dist = (float*)(ws + 0);
  float* bwpart = (float*)(ws + 1024);
  float* mmdpart = (float*)(ws + 3072);
  float* l2buf = (float*)(ws + 4096);
  float* wbuf = (float*)(ws + HDR);

  size_t avail = ws_size - HDR;
  int PC = (int)(avail / per_pair);
  if (PC > NPAIR) PC = NPAIR;

  for (int p0 = 0; p0 < NPAIR; p0 += PC) {
    int pc = (NPAIR - p0) < PC ? (NPAIR - p0) : PC;
    int first = (p0 == 0) ? 1 : 0;
    gemm_mmd_kernel<<<dim3(64, pc + first), 256, 0, stream>>>(
        data, wbuf, p0, pc, l2buf, bwpart);
    dtw_mmdk_kernel<<<dim3(pc + (first ? 121 : 0)), 64, 0, stream>>>(
        wbuf, lens, dist, p0, pc, l2buf, bwpart, mmdpart);
  }
  finalize_kernel<<<dim3(1), 64, 0, stream>>>(dist, mmdpart, out);
}